// Round 1
// baseline (1426.627 us; speedup 1.0000x reference)
//
#include <hip/hip_runtime.h>
#include <hip/hip_bf16.h>
#include <math.h>

#define NTOK   4096   // B*S
#define SEQ    1024
#define DMODEL 256
#define NHEAD  8
#define HDIM   32
#define FDIM   1024
#define NLAYER 4
#define NLET   22

// ---------------------------------------------------------------- reductions
__device__ __forceinline__ void blockSum2(float& s1, float& s2, float* red) {
    #pragma unroll
    for (int off = 32; off > 0; off >>= 1) {
        s1 += __shfl_down(s1, off);
        s2 += __shfl_down(s2, off);
    }
    int lane = threadIdx.x & 63, w = threadIdx.x >> 6;
    __syncthreads();                       // protect red from previous use
    if (lane == 0) { red[w] = s1; red[4 + w] = s2; }
    __syncthreads();
    s1 = red[0] + red[1] + red[2] + red[3];
    s2 = red[4] + red[5] + red[6] + red[7];
}

// ---------------------------------------------------------------- embedding
__global__ __launch_bounds__(256) void embed_kernel(
    const int* __restrict__ roots, const float* __restrict__ gem,
    const float* __restrict__ letE,
    const float* __restrict__ rpw, const float* __restrict__ rpb,
    const float* __restrict__ rlg, const float* __restrict__ rlb,
    const float* __restrict__ ipw, const float* __restrict__ ipb,
    const float* __restrict__ ilg, const float* __restrict__ ilb,
    float* __restrict__ x)
{
    __shared__ float cat[768];
    __shared__ float red[8];
    const int n = blockIdx.x, t = threadIdx.x;
    const int s = n & (SEQ - 1);
    const float LC = 0.0359778921f;   // ln(10000)/256

    int r0 = roots[n * 3 + 0], r1 = roots[n * 3 + 1], r2 = roots[n * 3 + 2];
    cat[t]       = letE[r0 * DMODEL + t];
    cat[256 + t] = letE[r1 * DMODEL + t];
    cat[512 + t] = letE[r2 * DMODEL + t];
    __syncthreads();

    float acc = rpb[t];
    for (int k = 0; k < 768; ++k) acc += cat[k] * rpw[k * DMODEL + t];

    float s1 = acc, s2 = acc * acc;
    blockSum2(s1, s2, red);
    float mean = s1 * (1.f / 256.f);
    float var  = s2 * (1.f / 256.f) - mean * mean;
    float rn = (acc - mean) * rsqrtf(var + 1e-5f) * rlg[t] + rlb[t];
    __syncthreads();                 // cat reads all done inside blockSum2's syncs
    cat[t] = rn;
    if (t < 128) {
        float g = gem[n];
        float ang = g * 500.f * expf(-(float)(2 * t) * LC);
        cat[256 + t] = sinf(ang);
        cat[384 + t] = cosf(ang);
    }
    __syncthreads();

    float acc2 = ipb[t];
    for (int k = 0; k < 512; ++k) acc2 += cat[k] * ipw[k * DMODEL + t];

    // flipped sinusoidal PE (interleaved sin/cos)
    float pos = (float)(SEQ - 1 - s);
    float dv = expf(-(float)(t & ~1) * LC);
    acc2 += (t & 1) ? cosf(pos * dv) : sinf(pos * dv);

    s1 = acc2; s2 = acc2 * acc2;
    blockSum2(s1, s2, red);
    mean = s1 * (1.f / 256.f);
    var  = s2 * (1.f / 256.f) - mean * mean;
    x[n * DMODEL + t] = (acc2 - mean) * rsqrtf(var + 1e-5f) * ilg[t] + ilb[t];
}

// ---------------------------------------------------------------- layernorm
__global__ __launch_bounds__(256) void ln_kernel(
    const float* __restrict__ in, float* __restrict__ out,
    const float* __restrict__ g, const float* __restrict__ b)
{
    __shared__ float red[8];
    const int n = blockIdx.x, t = threadIdx.x;
    float v = in[n * DMODEL + t];
    float s1 = v, s2 = v * v;
    blockSum2(s1, s2, red);
    float mean = s1 * (1.f / 256.f);
    float var  = s2 * (1.f / 256.f) - mean * mean;
    out[n * DMODEL + t] = (v - mean) * rsqrtf(var + 1e-5f) * g[t] + b[t];
}

// ---------------------------------------------------------------- GEMM
// C[N,M] = epi(A[N,K] @ W[K,M] + bias). EPI 0: store, 1: C += , 2: gelu store
template <int EPI>
__global__ __launch_bounds__(256) void gemm_kernel(
    const float* __restrict__ A, const float* __restrict__ W,
    const float* __restrict__ bias, float* __restrict__ C,
    int N, int K, int M)
{
    __shared__ float As[16][68];
    __shared__ float Bs[16][68];
    const int tid = threadIdx.x;
    const int tx = tid & 15;       // col quad
    const int ty = tid >> 4;       // row quad
    const int n0 = blockIdx.y * 64;
    const int m0 = blockIdx.x * 64;
    const int arow = tid >> 2, af = tid & 3;   // A stage
    const int bk = tid >> 4, bm = tid & 15;    // B stage

    float acc[4][4] = {};
    for (int k0 = 0; k0 < K; k0 += 16) {
        __syncthreads();
        float4 av = *(const float4*)(A + (long)(n0 + arow) * K + k0 + af * 4);
        As[af * 4 + 0][arow] = av.x;
        As[af * 4 + 1][arow] = av.y;
        As[af * 4 + 2][arow] = av.z;
        As[af * 4 + 3][arow] = av.w;
        *(float4*)(&Bs[bk][bm * 4]) = *(const float4*)(W + (long)(k0 + bk) * M + m0 + bm * 4);
        __syncthreads();
        #pragma unroll
        for (int k = 0; k < 16; ++k) {
            float a[4], b[4];
            #pragma unroll
            for (int i = 0; i < 4; ++i) a[i] = As[k][ty * 4 + i];
            #pragma unroll
            for (int j = 0; j < 4; ++j) b[j] = Bs[k][tx * 4 + j];
            #pragma unroll
            for (int i = 0; i < 4; ++i)
                #pragma unroll
                for (int j = 0; j < 4; ++j) acc[i][j] += a[i] * b[j];
        }
    }
    #pragma unroll
    for (int i = 0; i < 4; ++i) {
        int row = n0 + ty * 4 + i;
        #pragma unroll
        for (int j = 0; j < 4; ++j) {
            int col = m0 + tx * 4 + j;
            float v = acc[i][j] + bias[col];
            float* p = C + (long)row * M + col;
            if (EPI == 1) v += *p;
            if (EPI == 2) v = 0.5f * v * (1.f + erff(v * 0.70710678f));
            *p = v;
        }
    }
}

// ---------------------------------------------------------------- attention
// grid: (S/64, B*H). Flash-style over 64-key tiles; bias = -pen*|i-j|.
__global__ __launch_bounds__(256) void attn_kernel(
    const float* __restrict__ Q, const float* __restrict__ Kb,
    const float* __restrict__ Vb, float* __restrict__ O,
    const float* __restrict__ dist_scale, const float* __restrict__ diss_sens)
{
    __shared__ float Qs[64][36], Ks[64][36], Vs[64][36];
    __shared__ float Ss[64][65];
    const int tid = threadIdx.x;
    const int qt = blockIdx.x;
    const int bh = blockIdx.y;
    const int b = bh >> 3, h = bh & 7;
    const float pen = fabsf(dist_scale[h] * (1.f - 0.5f * diss_sens[h]));
    const int r = tid >> 2, c = tid & 3;
    const float scale = 0.17677669529663689f;   // 1/sqrt(32)

    const float* qbase = Q + (long)((b * SEQ + qt * 64 + r) * DMODEL) + h * HDIM;
    *(float4*)(&Qs[r][c * 8])     = *(const float4*)(qbase + c * 8);
    *(float4*)(&Qs[r][c * 8 + 4]) = *(const float4*)(qbase + c * 8 + 4);

    float m = -INFINITY, l = 0.f;
    float o[8] = {};
    const float qpos = (float)(qt * 64 + r);

    for (int kt = 0; kt < 16; ++kt) {
        __syncthreads();   // previous PV reads of Ks/Vs done; Qs ready (iter 0)
        const float* kbase = Kb + (long)((b * SEQ + kt * 64 + r) * DMODEL) + h * HDIM;
        const float* vbase = Vb + (long)((b * SEQ + kt * 64 + r) * DMODEL) + h * HDIM;
        *(float4*)(&Ks[r][c * 8])     = *(const float4*)(kbase + c * 8);
        *(float4*)(&Ks[r][c * 8 + 4]) = *(const float4*)(kbase + c * 8 + 4);
        *(float4*)(&Vs[r][c * 8])     = *(const float4*)(vbase + c * 8);
        *(float4*)(&Vs[r][c * 8 + 4]) = *(const float4*)(vbase + c * 8 + 4);
        __syncthreads();

        // scores: thread (r,c) handles keys krow = kk*4 + c
        float sc[16];
        float tmax = -INFINITY;
        #pragma unroll 4
        for (int kk = 0; kk < 16; ++kk) {
            int krow = kk * 4 + c;
            float acc = 0.f;
            #pragma unroll
            for (int d = 0; d < 32; ++d) acc += Qs[r][d] * Ks[krow][d];
            float kpos = (float)(kt * 64 + krow);
            acc = acc * scale - pen * fabsf(qpos - kpos);
            sc[kk] = acc;
            tmax = fmaxf(tmax, acc);
        }
        tmax = fmaxf(tmax, __shfl_xor(tmax, 1));
        tmax = fmaxf(tmax, __shfl_xor(tmax, 2));
        float mn  = fmaxf(m, tmax);
        float fac = expf(m - mn);       // first iter: exp(-inf)=0
        float ps = 0.f;
        #pragma unroll
        for (int kk = 0; kk < 16; ++kk) {
            float p = expf(sc[kk] - mn);
            Ss[r][kk * 4 + c] = p;
            ps += p;
        }
        ps += __shfl_xor(ps, 1);
        ps += __shfl_xor(ps, 2);
        l = l * fac + ps;
        m = mn;
        #pragma unroll
        for (int j = 0; j < 8; ++j) o[j] *= fac;
        __syncthreads();                // Ss complete
        #pragma unroll 8
        for (int kk = 0; kk < 64; ++kk) {
            float p = Ss[r][kk];
            #pragma unroll
            for (int j = 0; j < 8; ++j) o[j] += p * Vs[kk][c * 8 + j];
        }
    }
    float inv = 1.f / l;
    float* obase = O + (long)((b * SEQ + qt * 64 + r) * DMODEL) + h * HDIM + c * 8;
    #pragma unroll
    for (int j = 0; j < 8; ++j) obase[j] = o[j] * inv;
}

// ---------------------------------------------------------------- heads
__global__ __launch_bounds__(256) void head_kernel(
    const float* __restrict__ x, const float* __restrict__ g, const float* __restrict__ bb,
    const float* __restrict__ h1w, const float* __restrict__ h1b,
    const float* __restrict__ h2w, const float* __restrict__ h2b,
    const float* __restrict__ h3w, const float* __restrict__ h3b,
    float* __restrict__ out)
{
    __shared__ float xn[256];
    __shared__ float red[8];
    const int n = blockIdx.x, t = threadIdx.x;
    float v = x[n * DMODEL + t];
    float s1 = v, s2 = v * v;
    blockSum2(s1, s2, red);
    float mean = s1 * (1.f / 256.f);
    float var  = s2 * (1.f / 256.f) - mean * mean;
    xn[t] = (v - mean) * rsqrtf(var + 1e-5f) * g[t] + bb[t];
    __syncthreads();
    if (t < 66) {
        int head = t / NLET, j = t % NLET;
        const float* w  = (head == 0) ? h1w : (head == 1) ? h2w : h3w;
        const float* hb = (head == 0) ? h1b : (head == 1) ? h2b : h3b;
        float acc = hb[j];
        for (int k = 0; k < 256; ++k) acc += xn[k] * w[k * NLET + j];
        out[head * (NTOK * NLET) + n * NLET + j] = acc;
    }
}

// ---------------------------------------------------------------- launch
extern "C" void kernel_launch(void* const* d_in, const int* in_sizes, int n_in,
                              void* d_out, int out_size, void* d_ws, size_t ws_size,
                              hipStream_t stream)
{
    const int*   roots   = (const int*)  d_in[0];
    const float* gem     = (const float*)d_in[1];
    const float* letE    = (const float*)d_in[2];
    const float* rpw     = (const float*)d_in[3];
    const float* rpb     = (const float*)d_in[4];
    const float* rlg     = (const float*)d_in[5];
    const float* rlb     = (const float*)d_in[6];
    const float* ipw     = (const float*)d_in[7];
    const float* ipb     = (const float*)d_in[8];
    const float* ilg     = (const float*)d_in[9];
    const float* ilb     = (const float*)d_in[10];
    const float* qw      = (const float*)d_in[11];
    const float* qb      = (const float*)d_in[12];
    const float* kw      = (const float*)d_in[13];
    const float* kb      = (const float*)d_in[14];
    const float* vw      = (const float*)d_in[15];
    const float* vb      = (const float*)d_in[16];
    const float* ow      = (const float*)d_in[17];
    const float* ob      = (const float*)d_in[18];
    const float* dsc     = (const float*)d_in[19];
    const float* dss     = (const float*)d_in[20];
    const float* ff1w    = (const float*)d_in[21];
    const float* ff1b    = (const float*)d_in[22];
    const float* ff2w    = (const float*)d_in[23];
    const float* ff2b    = (const float*)d_in[24];
    const float* ln1g    = (const float*)d_in[25];
    const float* ln1b    = (const float*)d_in[26];
    const float* ln2g    = (const float*)d_in[27];
    const float* ln2b    = (const float*)d_in[28];
    const float* olng    = (const float*)d_in[29];
    const float* olnb    = (const float*)d_in[30];
    const float* h1w     = (const float*)d_in[31];
    const float* h1b     = (const float*)d_in[32];
    const float* h2w     = (const float*)d_in[33];
    const float* h2b     = (const float*)d_in[34];
    const float* h3w     = (const float*)d_in[35];
    const float* h3b     = (const float*)d_in[36];

    float* ws  = (float*)d_ws;
    const long SZ = (long)NTOK * DMODEL;     // 1M floats
    float* x   = ws + 0 * SZ;
    float* nrm = ws + 1 * SZ;
    float* q   = ws + 2 * SZ;
    float* k   = ws + 3 * SZ;
    float* v   = ws + 4 * SZ;
    float* ao  = ws + 5 * SZ;
    float* hb  = ws + 6 * SZ;                // 4M floats (N x F)

    embed_kernel<<<NTOK, 256, 0, stream>>>(roots, gem, letE, rpw, rpb, rlg, rlb,
                                           ipw, ipb, ilg, ilb, x);
    for (int l = 0; l < NLAYER; ++l) {
        ln_kernel<<<NTOK, 256, 0, stream>>>(x, nrm, ln1g + l * DMODEL, ln1b + l * DMODEL);
        dim3 g1(DMODEL / 64, NTOK / 64);
        gemm_kernel<0><<<g1, 256, 0, stream>>>(nrm, qw + l * DMODEL * DMODEL, qb + l * DMODEL, q, NTOK, DMODEL, DMODEL);
        gemm_kernel<0><<<g1, 256, 0, stream>>>(nrm, kw + l * DMODEL * DMODEL, kb + l * DMODEL, k, NTOK, DMODEL, DMODEL);
        gemm_kernel<0><<<g1, 256, 0, stream>>>(nrm, vw + l * DMODEL * DMODEL, vb + l * DMODEL, v, NTOK, DMODEL, DMODEL);
        dim3 ga(SEQ / 64, 4 * NHEAD);
        attn_kernel<<<ga, 256, 0, stream>>>(q, k, v, ao, dsc + l * NHEAD, dss + l * NHEAD);
        gemm_kernel<1><<<g1, 256, 0, stream>>>(ao, ow + l * DMODEL * DMODEL, ob + l * DMODEL, x, NTOK, DMODEL, DMODEL);
        ln_kernel<<<NTOK, 256, 0, stream>>>(x, nrm, ln2g + l * DMODEL, ln2b + l * DMODEL);
        dim3 g2(FDIM / 64, NTOK / 64);
        gemm_kernel<2><<<g2, 256, 0, stream>>>(nrm, ff1w + l * DMODEL * FDIM, ff1b + l * FDIM, hb, NTOK, DMODEL, FDIM);
        gemm_kernel<1><<<g1, 256, 0, stream>>>(hb, ff2w + l * FDIM * DMODEL, ff2b + l * DMODEL, x, NTOK, FDIM, DMODEL);
    }
    head_kernel<<<NTOK, 256, 0, stream>>>(x, olng, olnb, h1w, h1b, h2w, h2b, h3w, h3b,
                                          (float*)d_out);
}

// Round 2
// 569.605 us; speedup vs baseline: 2.5046x; 2.5046x over previous
//
#include <hip/hip_runtime.h>
#include <hip/hip_bf16.h>
#include <math.h>

#define NTOK   4096
#define SEQ    1024
#define DMODEL 256
#define NHEAD  8
#define FDIM   1024
#define NLAYER 4

typedef __attribute__((ext_vector_type(8))) short short8v;
typedef __attribute__((ext_vector_type(4))) float f32x4;

#define LDS3(p) ((__attribute__((address_space(3))) unsigned int*)(p))
#define GAS1(p) ((const __attribute__((address_space(1))) unsigned int*)(p))

__device__ __forceinline__ void gl_lds16(const void* g, void* l) {
    __builtin_amdgcn_global_load_lds(GAS1(g), LDS3(l), 16, 0, 0);
}
__device__ __forceinline__ short f2bf(float v) {
    __hip_bfloat16 h = __float2bfloat16(v);
    return __builtin_bit_cast(short, h);
}

// ---------------------------------------------------------------- reductions
__device__ __forceinline__ void blockSum2(float& s1, float& s2, float* red) {
    #pragma unroll
    for (int off = 32; off > 0; off >>= 1) {
        s1 += __shfl_down(s1, off);
        s2 += __shfl_down(s2, off);
    }
    int lane = threadIdx.x & 63, w = threadIdx.x >> 6;
    __syncthreads();
    if (lane == 0) { red[w] = s1; red[4 + w] = s2; }
    __syncthreads();
    s1 = red[0] + red[1] + red[2] + red[3];
    s2 = red[4] + red[5] + red[6] + red[7];
}

// ---------------------------------------------------------------- weight transpose fp32[K][M] -> bf16[M][K]
struct TD { const float* src; __hip_bfloat16* dst; int K; int M; };
struct TDs { TD d[29]; };

__global__ __launch_bounds__(256) void transpose_kernel(TDs p) {
    __shared__ float ld[32][33];
    TD d = p.d[blockIdx.y];
    int tm = (d.M + 31) >> 5;
    int kt = blockIdx.x / tm, mt = blockIdx.x % tm;
    if (kt * 32 >= d.K) return;
    int tx = threadIdx.x & 31, ty = threadIdx.x >> 5;
    #pragma unroll
    for (int r = 0; r < 4; ++r) {
        int k = kt * 32 + ty + r * 8, m = mt * 32 + tx;
        if (m < d.M) ld[ty + r * 8][tx] = d.src[(long)k * d.M + m];
    }
    __syncthreads();
    #pragma unroll
    for (int r = 0; r < 4; ++r) {
        int m = mt * 32 + ty + r * 8, k = kt * 32 + tx;
        if (m < d.M) d.dst[(long)m * d.K + k] = __float2bfloat16(ld[tx][ty + r * 8]);
    }
}

// ---------------------------------------------------------------- MFMA GEMM
// C[N,M] = epi(A[N,K] @ Wt[M,K]^T + bias)
// EPI 0: fp32 store | 1: fp32 residual add | 2: gelu->bf16 | 3: bf16 store
//     4: V store transposed per head | 5: heads scatter (cols<66)
template <int TM, int TN, int EPI>
__global__ __launch_bounds__(256) void mm_kernel(
    const __hip_bfloat16* __restrict__ A, const __hip_bfloat16* __restrict__ Bw,
    const float* __restrict__ bias, float* __restrict__ Cf,
    __hip_bfloat16* __restrict__ Cb, int N, int K, int M)
{
    constexpr int BK = 64;
    __shared__ __align__(16) short As[TM * BK];
    __shared__ __align__(16) short Bs[TN * BK];
    const int tid = threadIdx.x;
    const int lane = tid & 63, wid = tid >> 6;
    const int wr = wid >> 1, wc = wid & 1;
    const int n0 = blockIdx.y * TM, m0 = blockIdx.x * TN;
    const int l15 = lane & 15, g = lane >> 4;
    constexpr int FM = TM / 32, FN = TN / 32;
    f32x4 acc[FM][FN] = {};

    for (int k0 = 0; k0 < K; k0 += BK) {
        constexpr int CA = TM * 8;      // 16B chunks in A tile
        #pragma unroll
        for (int j = 0; j < CA / 256; ++j) {
            int cid = tid + j * 256;
            int r = cid >> 3, sl = cid & 7, ss = sl ^ (r & 7);
            gl_lds16(A + (long)(n0 + r) * K + k0 + ss * 8, (char*)As + cid * 16);
        }
        constexpr int CB = TN * 8;
        #pragma unroll
        for (int j = 0; j < CB / 256; ++j) {
            int cid = tid + j * 256;
            int r = cid >> 3, sl = cid & 7, ss = sl ^ (r & 7);
            gl_lds16(Bw + (long)(m0 + r) * K + k0 + ss * 8, (char*)Bs + cid * 16);
        }
        __syncthreads();
        #pragma unroll
        for (int ks = 0; ks < 2; ++ks) {
            short8v af[FM], bfr[FN];
            #pragma unroll
            for (int mi = 0; mi < FM; ++mi) {
                int row = wr * (TM / 2) + mi * 16 + l15;
                int slot = (ks * 4 + g) ^ (row & 7);
                af[mi] = *(const short8v*)((const char*)As + row * (BK * 2) + slot * 16);
            }
            #pragma unroll
            for (int ni = 0; ni < FN; ++ni) {
                int row = wc * (TN / 2) + ni * 16 + l15;
                int slot = (ks * 4 + g) ^ (row & 7);
                bfr[ni] = *(const short8v*)((const char*)Bs + row * (BK * 2) + slot * 16);
            }
            #pragma unroll
            for (int mi = 0; mi < FM; ++mi)
                #pragma unroll
                for (int ni = 0; ni < FN; ++ni)
                    acc[mi][ni] = __builtin_amdgcn_mfma_f32_16x16x32_bf16(
                        af[mi], bfr[ni], acc[mi][ni], 0, 0, 0);
        }
        __syncthreads();
    }

    #pragma unroll
    for (int mi = 0; mi < FM; ++mi) {
        #pragma unroll
        for (int ni = 0; ni < FN; ++ni) {
            int colb = m0 + wc * (TN / 2) + ni * 16 + l15;
            float bv = bias[colb];
            if (EPI == 4) {
                int h = colb >> 5, dd = colb & 31;
                int row0 = n0 + wr * (TM / 2) + mi * 16 + g * 4;
                int bb = row0 >> 10, ss = row0 & 1023;
                short4 pk;
                pk.x = f2bf(acc[mi][ni][0] + bv);
                pk.y = f2bf(acc[mi][ni][1] + bv);
                pk.z = f2bf(acc[mi][ni][2] + bv);
                pk.w = f2bf(acc[mi][ni][3] + bv);
                *(short4*)((short*)Cb + ((long)((bb * 8 + h) * 32 + dd) << 10) + ss) = pk;
            } else {
                #pragma unroll
                for (int i = 0; i < 4; ++i) {
                    int row = n0 + wr * (TM / 2) + mi * 16 + g * 4 + i;
                    float v = acc[mi][ni][i] + bv;
                    if (EPI == 0) Cf[(long)row * M + colb] = v;
                    else if (EPI == 1) Cf[(long)row * M + colb] += v;
                    else if (EPI == 2) {
                        v = 0.5f * v * (1.f + erff(v * 0.70710678f));
                        Cb[(long)row * M + colb] = __float2bfloat16(v);
                    } else if (EPI == 3) Cb[(long)row * M + colb] = __float2bfloat16(v);
                    else if (EPI == 5) {
                        if (colb < 66) {
                            int hd = colb / 22, jj = colb - hd * 22;
                            Cf[(long)hd * (NTOK * 22) + (long)row * 22 + jj] = v;
                        }
                    }
                }
            }
        }
    }
}

// ---------------------------------------------------------------- MFMA flash attention
// grid (SEQ/64, B*NHEAD); Q,K bf16 [4096][256]; Vt bf16 [32 bh][32 d][1024 s]
__global__ __launch_bounds__(256) void attn_mfma_kernel(
    const __hip_bfloat16* __restrict__ Q, const __hip_bfloat16* __restrict__ Kx,
    const __hip_bfloat16* __restrict__ Vt, __hip_bfloat16* __restrict__ Oa,
    const float* __restrict__ dsc, const float* __restrict__ dss)
{
    __shared__ __align__(16) short Qs[64 * 32];
    __shared__ __align__(16) short Ks[64 * 32];
    __shared__ __align__(16) short Vs[32 * 64];
    __shared__ __align__(16) short Ps[4 * 16 * 64];
    const int tid = threadIdx.x, lane = tid & 63, wid = tid >> 6;
    const int qt = blockIdx.x, bh = blockIdx.y, b = bh >> 3, h = bh & 7;
    const float pen = fabsf(dsc[h] * (1.f - 0.5f * dss[h]));
    const int l15 = lane & 15, g = lane >> 4;
    const float scale = 0.17677669529663689f;

    {   // stage Q tile (64 rows x 32 d)
        int r = tid >> 2, sl = tid & 3, ss = sl ^ (r & 3);
        gl_lds16(Q + ((long)(b * SEQ + qt * 64 + r) * DMODEL + h * 32) + ss * 8,
                 (char*)Qs + tid * 16);
    }
    float mrow[4], lrow[4];
    #pragma unroll
    for (int i = 0; i < 4; ++i) { mrow[i] = -1e30f; lrow[i] = 0.f; }
    f32x4 oacc[2] = {};
    float qpos[4];
    #pragma unroll
    for (int i = 0; i < 4; ++i) qpos[i] = (float)(qt * 64 + wid * 16 + g * 4 + i);

    for (int kt = 0; kt < 16; ++kt) {
        {
            int r = tid >> 2, sl = tid & 3, ss = sl ^ (r & 3);
            gl_lds16(Kx + ((long)(b * SEQ + kt * 64 + r) * DMODEL + h * 32) + ss * 8,
                     (char*)Ks + tid * 16);
            int d = tid >> 3, sl8 = tid & 7, ss8 = sl8 ^ (d & 7);
            gl_lds16(Vt + ((long)(bh * 32 + d) << 10) + kt * 64 + ss8 * 8,
                     (char*)Vs + tid * 16);
        }
        __syncthreads();

        short8v aq;
        {
            int row = wid * 16 + l15;
            int slot = g ^ (row & 3);
            aq = *(const short8v*)((const char*)Qs + row * 64 + slot * 16);
        }
        f32x4 sa[4];
        #pragma unroll
        for (int ni = 0; ni < 4; ++ni) {
            int krow = ni * 16 + l15;
            int slot = g ^ (krow & 3);
            short8v bk = *(const short8v*)((const char*)Ks + krow * 64 + slot * 16);
            f32x4 z = {0.f, 0.f, 0.f, 0.f};
            sa[ni] = __builtin_amdgcn_mfma_f32_16x16x32_bf16(aq, bk, z, 0, 0, 0);
        }
        float sc[4][4], tmax[4];
        #pragma unroll
        for (int i = 0; i < 4; ++i) tmax[i] = -1e30f;
        #pragma unroll
        for (int ni = 0; ni < 4; ++ni) {
            float kpos = (float)(kt * 64 + ni * 16 + l15);
            #pragma unroll
            for (int i = 0; i < 4; ++i) {
                float v = sa[ni][i] * scale - pen * fabsf(qpos[i] - kpos);
                sc[ni][i] = v;
                tmax[i] = fmaxf(tmax[i], v);
            }
        }
        #pragma unroll
        for (int i = 0; i < 4; ++i) {
            #pragma unroll
            for (int off = 8; off; off >>= 1)
                tmax[i] = fmaxf(tmax[i], __shfl_xor(tmax[i], off));
        }
        float fac[4];
        #pragma unroll
        for (int i = 0; i < 4; ++i) {
            float mn = fmaxf(mrow[i], tmax[i]);
            fac[i] = __expf(mrow[i] - mn);
            mrow[i] = mn;
        }
        float ps[4] = {0.f, 0.f, 0.f, 0.f};
        #pragma unroll
        for (int ni = 0; ni < 4; ++ni) {
            #pragma unroll
            for (int i = 0; i < 4; ++i) {
                float p = __expf(sc[ni][i] - mrow[i]);
                ps[i] += p;
                int lr = g * 4 + i, key = ni * 16 + l15;
                int slot = (key >> 3) ^ (lr & 7);
                *(short*)((char*)Ps + wid * 2048 + lr * 128 + slot * 16 + (key & 7) * 2) = f2bf(p);
            }
        }
        #pragma unroll
        for (int i = 0; i < 4; ++i) {
            #pragma unroll
            for (int off = 8; off; off >>= 1) ps[i] += __shfl_xor(ps[i], off);
            lrow[i] = lrow[i] * fac[i] + ps[i];
        }
        #pragma unroll
        for (int n2 = 0; n2 < 2; ++n2)
            #pragma unroll
            for (int i = 0; i < 4; ++i) oacc[n2][i] *= fac[i];

        #pragma unroll
        for (int ks = 0; ks < 2; ++ks) {
            int lr = l15;
            int slot = (ks * 4 + g) ^ (lr & 7);
            short8v pa = *(const short8v*)((const char*)Ps + wid * 2048 + lr * 128 + slot * 16);
            #pragma unroll
            for (int n2 = 0; n2 < 2; ++n2) {
                int d = n2 * 16 + l15;
                int vslot = (ks * 4 + g) ^ (d & 7);
                short8v vb = *(const short8v*)((const char*)Vs + d * 128 + vslot * 16);
                oacc[n2] = __builtin_amdgcn_mfma_f32_16x16x32_bf16(pa, vb, oacc[n2], 0, 0, 0);
            }
        }
        __syncthreads();
    }
    #pragma unroll
    for (int n2 = 0; n2 < 2; ++n2) {
        #pragma unroll
        for (int i = 0; i < 4; ++i) {
            float v = oacc[n2][i] / lrow[i];
            long row = b * SEQ + qt * 64 + wid * 16 + g * 4 + i;
            Oa[row * DMODEL + h * 32 + n2 * 16 + l15] = __float2bfloat16(v);
        }
    }
}

// ---------------------------------------------------------------- small fused kernels
__global__ __launch_bounds__(256) void gather_kernel(
    const int* __restrict__ roots, const float* __restrict__ letE,
    __hip_bfloat16* __restrict__ cat,
    const float* __restrict__ h1b, const float* __restrict__ h2b,
    const float* __restrict__ h3b, float* __restrict__ biascat)
{
    const int n = blockIdx.x, t = threadIdx.x;
    int r0 = roots[n * 3 + 0], r1 = roots[n * 3 + 1], r2 = roots[n * 3 + 2];
    cat[(long)n * 768 + t]       = __float2bfloat16(letE[r0 * DMODEL + t]);
    cat[(long)n * 768 + 256 + t] = __float2bfloat16(letE[r1 * DMODEL + t]);
    cat[(long)n * 768 + 512 + t] = __float2bfloat16(letE[r2 * DMODEL + t]);
    if (n == 0 && t < 66)
        biascat[t] = (t < 22) ? h1b[t] : (t < 44) ? h2b[t - 22] : h3b[t - 44];
}

// LN(tmpf)*rlg+rlb -> catin[:,0:256]; gematria sinusoid -> catin[:,256:512]
__global__ __launch_bounds__(256) void ln_gem_kernel(
    const float* __restrict__ tmpf, const float* __restrict__ gem,
    const float* __restrict__ gg, const float* __restrict__ gb,
    __hip_bfloat16* __restrict__ catin)
{
    __shared__ float red[8];
    const int n = blockIdx.x, t = threadIdx.x;
    const float LC = 0.0359778921f;
    float v = tmpf[(long)n * DMODEL + t];
    float s1 = v, s2 = v * v;
    blockSum2(s1, s2, red);
    float mean = s1 * (1.f / 256.f);
    float var = s2 * (1.f / 256.f) - mean * mean;
    catin[(long)n * 512 + t] =
        __float2bfloat16((v - mean) * rsqrtf(var + 1e-5f) * gg[t] + gb[t]);
    float gv = gem[n];
    int j = (t < 128) ? t : t - 128;
    float ang = gv * 500.f * expf(-(float)(2 * j) * LC);
    catin[(long)n * 512 + 256 + t] = __float2bfloat16((t < 128) ? sinf(ang) : cosf(ang));
}

// x = LN(tmpf + PE)
__global__ __launch_bounds__(256) void ln_pe_kernel(
    const float* __restrict__ tmpf, const float* __restrict__ gg,
    const float* __restrict__ gb, float* __restrict__ x)
{
    __shared__ float red[8];
    const int n = blockIdx.x, t = threadIdx.x;
    const int s = n & (SEQ - 1);
    const float LC = 0.0359778921f;
    float pos = (float)(SEQ - 1 - s);
    float dv = expf(-(float)(t & ~1) * LC);
    float pe = (t & 1) ? cosf(pos * dv) : sinf(pos * dv);
    float v = tmpf[(long)n * DMODEL + t] + pe;
    float s1 = v, s2 = v * v;
    blockSum2(s1, s2, red);
    float mean = s1 * (1.f / 256.f);
    float var = s2 * (1.f / 256.f) - mean * mean;
    x[(long)n * DMODEL + t] = (v - mean) * rsqrtf(var + 1e-5f) * gg[t] + gb[t];
}

// LN fp32 -> bf16
__global__ __launch_bounds__(256) void ln_bf_kernel(
    const float* __restrict__ in, __hip_bfloat16* __restrict__ out,
    const float* __restrict__ gg, const float* __restrict__ gb)
{
    __shared__ float red[8];
    const int n = blockIdx.x, t = threadIdx.x;
    float v = in[(long)n * DMODEL + t];
    float s1 = v, s2 = v * v;
    blockSum2(s1, s2, red);
    float mean = s1 * (1.f / 256.f);
    float var = s2 * (1.f / 256.f) - mean * mean;
    out[(long)n * DMODEL + t] =
        __float2bfloat16((v - mean) * rsqrtf(var + 1e-5f) * gg[t] + gb[t]);
}

// ---------------------------------------------------------------- launch
extern "C" void kernel_launch(void* const* d_in, const int* in_sizes, int n_in,
                              void* d_out, int out_size, void* d_ws, size_t ws_size,
                              hipStream_t stream)
{
    const int*   roots = (const int*)  d_in[0];
    const float* gem   = (const float*)d_in[1];
    const float* letE  = (const float*)d_in[2];
    const float* rpw   = (const float*)d_in[3];
    const float* rpb   = (const float*)d_in[4];
    const float* rlg   = (const float*)d_in[5];
    const float* rlb   = (const float*)d_in[6];
    const float* ipw   = (const float*)d_in[7];
    const float* ipb   = (const float*)d_in[8];
    const float* ilg   = (const float*)d_in[9];
    const float* ilb   = (const float*)d_in[10];
    const float* qw    = (const float*)d_in[11];
    const float* qb    = (const float*)d_in[12];
    const float* kw    = (const float*)d_in[13];
    const float* kb    = (const float*)d_in[14];
    const float* vw    = (const float*)d_in[15];
    const float* vb    = (const float*)d_in[16];
    const float* ow    = (const float*)d_in[17];
    const float* ob    = (const float*)d_in[18];
    const float* dsc   = (const float*)d_in[19];
    const float* dss   = (const float*)d_in[20];
    const float* ff1w  = (const float*)d_in[21];
    const float* ff1b  = (const float*)d_in[22];
    const float* ff2w  = (const float*)d_in[23];
    const float* ff2b  = (const float*)d_in[24];
    const float* ln1g  = (const float*)d_in[25];
    const float* ln1b  = (const float*)d_in[26];
    const float* ln2g  = (const float*)d_in[27];
    const float* ln2b  = (const float*)d_in[28];
    const float* olng  = (const float*)d_in[29];
    const float* olnb  = (const float*)d_in[30];
    const float* h1w   = (const float*)d_in[31];
    const float* h1b   = (const float*)d_in[32];
    const float* h2w   = (const float*)d_in[33];
    const float* h2b   = (const float*)d_in[34];
    const float* h3w   = (const float*)d_in[35];
    const float* h3b   = (const float*)d_in[36];

    char* wsb = (char*)d_ws;
    float*          x    = (float*)         (wsb + (0l  << 20));
    float*          tmpf = (float*)         (wsb + (4l  << 20));
    __hip_bfloat16* nrm  = (__hip_bfloat16*)(wsb + (8l  << 20));
    __hip_bfloat16* qbuf = (__hip_bfloat16*)(wsb + (10l << 20));
    __hip_bfloat16* kbuf = (__hip_bfloat16*)(wsb + (12l << 20));
    __hip_bfloat16* vtb  = (__hip_bfloat16*)(wsb + (14l << 20));
    __hip_bfloat16* aob  = (__hip_bfloat16*)(wsb + (16l << 20));
    __hip_bfloat16* hbb  = (__hip_bfloat16*)(wsb + (18l << 20));
    __hip_bfloat16* catb  = hbb;     // alias (embed phase only)
    __hip_bfloat16* catin = qbuf;    // alias (embed phase only, spans q+k)
    __hip_bfloat16* wb   = (__hip_bfloat16*)(wsb + (26l << 20));
    float*          biascat = (float*)      (wsb + (34l << 20));

    // bf16 transposed weight offsets (elements)
    __hip_bfloat16* rpw_t  = wb;
    __hip_bfloat16* ipw_t  = wb + 196608;
    __hip_bfloat16* qw_t   = wb + 327680;
    __hip_bfloat16* kw_t   = wb + 589824;
    __hip_bfloat16* vw_t   = wb + 851968;
    __hip_bfloat16* ow_t   = wb + 1114112;
    __hip_bfloat16* ff1w_t = wb + 1376256;
    __hip_bfloat16* ff2w_t = wb + 2424832;
    __hip_bfloat16* head_t = wb + 3473408;

    hipMemsetAsync(head_t, 0, 32768 * 2, stream);

    TDs td;
    td.d[0] = {rpw, rpw_t, 768, 256};
    td.d[1] = {ipw, ipw_t, 512, 256};
    for (int l = 0; l < 4; ++l) {
        td.d[2 + l]  = {qw + l * 65536,  qw_t + l * 65536,  256, 256};
        td.d[6 + l]  = {kw + l * 65536,  kw_t + l * 65536,  256, 256};
        td.d[10 + l] = {vw + l * 65536,  vw_t + l * 65536,  256, 256};
        td.d[14 + l] = {ow + l * 65536,  ow_t + l * 65536,  256, 256};
        td.d[18 + l] = {ff1w + l * 262144, ff1w_t + l * 262144, 256, 1024};
        td.d[22 + l] = {ff2w + l * 262144, ff2w_t + l * 262144, 1024, 256};
    }
    td.d[26] = {h1w, head_t + 0 * 22 * 256, 256, 22};
    td.d[27] = {h2w, head_t + 1 * 22 * 256, 256, 22};
    td.d[28] = {h3w, head_t + 2 * 22 * 256, 256, 22};
    transpose_kernel<<<dim3(256, 29), 256, 0, stream>>>(td);

    gather_kernel<<<NTOK, 256, 0, stream>>>(roots, letE, catb, h1b, h2b, h3b, biascat);
    mm_kernel<64, 64, 0><<<dim3(4, 64), 256, 0, stream>>>(catb, rpw_t, rpb, tmpf, nullptr, NTOK, 768, 256);
    ln_gem_kernel<<<NTOK, 256, 0, stream>>>(tmpf, gem, rlg, rlb, catin);
    mm_kernel<64, 64, 0><<<dim3(4, 64), 256, 0, stream>>>(catin, ipw_t, ipb, tmpf, nullptr, NTOK, 512, 256);
    ln_pe_kernel<<<NTOK, 256, 0, stream>>>(tmpf, ilg, ilb, x);

    for (int l = 0; l < NLAYER; ++l) {
        ln_bf_kernel<<<NTOK, 256, 0, stream>>>(x, nrm, ln1g + l * 256, ln1b + l * 256);
        mm_kernel<64, 64, 3><<<dim3(4, 64), 256, 0, stream>>>(nrm, qw_t + l * 65536, qb + l * 256, nullptr, qbuf, NTOK, 256, 256);
        mm_kernel<64, 64, 3><<<dim3(4, 64), 256, 0, stream>>>(nrm, kw_t + l * 65536, kb + l * 256, nullptr, kbuf, NTOK, 256, 256);
        mm_kernel<64, 64, 4><<<dim3(4, 64), 256, 0, stream>>>(nrm, vw_t + l * 65536, vb + l * 256, nullptr, vtb, NTOK, 256, 256);
        attn_mfma_kernel<<<dim3(16, 32), 256, 0, stream>>>(qbuf, kbuf, vtb, aob, dsc + l * 8, dss + l * 8);
        mm_kernel<64, 64, 1><<<dim3(4, 64), 256, 0, stream>>>(aob, ow_t + l * 65536, ob + l * 256, x, nullptr, NTOK, 256, 256);
        ln_bf_kernel<<<NTOK, 256, 0, stream>>>(x, nrm, ln2g + l * 256, ln2b + l * 256);
        mm_kernel<128, 128, 2><<<dim3(8, 32), 256, 0, stream>>>(nrm, ff1w_t + l * 262144, ff1b + l * 1024, nullptr, hbb, NTOK, 256, 1024);
        mm_kernel<64, 64, 1><<<dim3(4, 64), 256, 0, stream>>>(hbb, ff2w_t + l * 262144, ff2b + l * 256, x, nullptr, NTOK, 1024, 256);
    }
    ln_bf_kernel<<<NTOK, 256, 0, stream>>>(x, nrm, olng, olnb);
    mm_kernel<64, 64, 5><<<dim3(2, 64), 256, 0, stream>>>(nrm, head_t, biascat, (float*)d_out, nullptr, NTOK, 256, 128);
}

// Round 3
// 525.591 us; speedup vs baseline: 2.7143x; 1.0837x over previous
//
#include <hip/hip_runtime.h>
#include <hip/hip_bf16.h>
#include <math.h>

#define NTOK   4096
#define SEQ    1024
#define DMODEL 256
#define NHEAD  8
#define FDIM   1024
#define NLAYER 4

typedef __attribute__((ext_vector_type(8))) short short8v;
typedef __attribute__((ext_vector_type(4))) float f32x4;

#define LDS3(p) ((__attribute__((address_space(3))) unsigned int*)(p))
#define GAS1(p) ((const __attribute__((address_space(1))) unsigned int*)(p))

__device__ __forceinline__ void gl_lds16(const void* g, void* l) {
    __builtin_amdgcn_global_load_lds(GAS1(g), LDS3(l), 16, 0, 0);
}
__device__ __forceinline__ short f2bf(float v) {
    __hip_bfloat16 h = __float2bfloat16(v);
    return __builtin_bit_cast(short, h);
}

// ---------------------------------------------------------------- reductions
__device__ __forceinline__ void blockSum2(float& s1, float& s2, float* red) {
    #pragma unroll
    for (int off = 32; off > 0; off >>= 1) {
        s1 += __shfl_down(s1, off);
        s2 += __shfl_down(s2, off);
    }
    int lane = threadIdx.x & 63, w = threadIdx.x >> 6;
    __syncthreads();
    if (lane == 0) { red[w] = s1; red[4 + w] = s2; }
    __syncthreads();
    s1 = red[0] + red[1] + red[2] + red[3];
    s2 = red[4] + red[5] + red[6] + red[7];
}

// ---------------------------------------------------------------- weight transpose fp32[K][M] -> bf16[M][K]
struct TD { const float* src; __hip_bfloat16* dst; int K; int M; };
struct TDs { TD d[29]; };

__global__ __launch_bounds__(256) void transpose_kernel(TDs p) {
    __shared__ float ld[32][33];
    TD d = p.d[blockIdx.y];
    int tm = (d.M + 31) >> 5;
    int kt = blockIdx.x / tm, mt = blockIdx.x % tm;
    if (kt * 32 >= d.K) return;
    int tx = threadIdx.x & 31, ty = threadIdx.x >> 5;
    #pragma unroll
    for (int r = 0; r < 4; ++r) {
        int k = kt * 32 + ty + r * 8, m = mt * 32 + tx;
        if (m < d.M) ld[ty + r * 8][tx] = d.src[(long)k * d.M + m];
    }
    __syncthreads();
    #pragma unroll
    for (int r = 0; r < 4; ++r) {
        int m = mt * 32 + ty + r * 8, k = kt * 32 + tx;
        if (m < d.M) d.dst[(long)m * d.K + k] = __float2bfloat16(ld[tx][ty + r * 8]);
    }
}

// ---------------------------------------------------------------- MFMA GEMM (generic tile)
// EPI 0: fp32 store | 2: gelu->bf16 | 5: heads scatter (cols<66) | 6: QKV split
template <int TM, int TN, int EPI>
__global__ __launch_bounds__(256) void mm_kernel(
    const __hip_bfloat16* __restrict__ A, const __hip_bfloat16* __restrict__ Bw,
    const float* __restrict__ bias, float* __restrict__ Cf,
    __hip_bfloat16* __restrict__ Cb, int N, int K, int M,
    const float* __restrict__ b2, const float* __restrict__ b3,
    __hip_bfloat16* __restrict__ Ck, __hip_bfloat16* __restrict__ Cv)
{
    constexpr int BK = 64;
    __shared__ __align__(16) short As[TM * BK];
    __shared__ __align__(16) short Bs[TN * BK];
    const int tid = threadIdx.x;
    const int lane = tid & 63, wid = tid >> 6;
    const int wr = wid >> 1, wc = wid & 1;
    const int n0 = blockIdx.y * TM, m0 = blockIdx.x * TN;
    const int l15 = lane & 15, g = lane >> 4;
    constexpr int FM = TM / 32, FN = TN / 32;
    f32x4 acc[FM][FN] = {};

    for (int k0 = 0; k0 < K; k0 += BK) {
        constexpr int CA = TM * 8;
        __syncthreads();
        #pragma unroll
        for (int j = 0; j < CA / 256; ++j) {
            int cid = tid + j * 256;
            int r = cid >> 3, sl = cid & 7, ss = sl ^ (r & 7);
            gl_lds16(A + (long)(n0 + r) * K + k0 + ss * 8, (char*)As + cid * 16);
        }
        constexpr int CB = TN * 8;
        #pragma unroll
        for (int j = 0; j < CB / 256; ++j) {
            int cid = tid + j * 256;
            int r = cid >> 3, sl = cid & 7, ss = sl ^ (r & 7);
            gl_lds16(Bw + (long)(m0 + r) * K + k0 + ss * 8, (char*)Bs + cid * 16);
        }
        __syncthreads();
        #pragma unroll
        for (int ks = 0; ks < 2; ++ks) {
            short8v af[FM], bfr[FN];
            #pragma unroll
            for (int mi = 0; mi < FM; ++mi) {
                int row = wr * (TM / 2) + mi * 16 + l15;
                int slot = (ks * 4 + g) ^ (row & 7);
                af[mi] = *(const short8v*)((const char*)As + row * (BK * 2) + slot * 16);
            }
            #pragma unroll
            for (int ni = 0; ni < FN; ++ni) {
                int row = wc * (TN / 2) + ni * 16 + l15;
                int slot = (ks * 4 + g) ^ (row & 7);
                bfr[ni] = *(const short8v*)((const char*)Bs + row * (BK * 2) + slot * 16);
            }
            #pragma unroll
            for (int mi = 0; mi < FM; ++mi)
                #pragma unroll
                for (int ni = 0; ni < FN; ++ni)
                    acc[mi][ni] = __builtin_amdgcn_mfma_f32_16x16x32_bf16(
                        af[mi], bfr[ni], acc[mi][ni], 0, 0, 0);
        }
    }

    #pragma unroll
    for (int mi = 0; mi < FM; ++mi) {
        #pragma unroll
        for (int ni = 0; ni < FN; ++ni) {
            int colb = m0 + wc * (TN / 2) + ni * 16 + l15;
            float bv;
            if (EPI == 6) bv = (colb < 256) ? bias[colb] : (colb < 512) ? b2[colb - 256] : b3[colb - 512];
            else bv = bias[colb];
            if (EPI == 6 && colb >= 512) {
                int c2 = colb - 512;
                int h = c2 >> 5, dd = c2 & 31;
                int row0 = n0 + wr * (TM / 2) + mi * 16 + g * 4;
                int bb = row0 >> 10, ss = row0 & 1023;
                short4 pk;
                pk.x = f2bf(acc[mi][ni][0] + bv);
                pk.y = f2bf(acc[mi][ni][1] + bv);
                pk.z = f2bf(acc[mi][ni][2] + bv);
                pk.w = f2bf(acc[mi][ni][3] + bv);
                *(short4*)((short*)Cv + ((long)((bb * 8 + h) * 32 + dd) << 10) + ss) = pk;
            } else {
                #pragma unroll
                for (int i = 0; i < 4; ++i) {
                    int row = n0 + wr * (TM / 2) + mi * 16 + g * 4 + i;
                    float v = acc[mi][ni][i] + bv;
                    if (EPI == 0) Cf[(long)row * M + colb] = v;
                    else if (EPI == 2) {
                        v = 0.5f * v * (1.f + erff(v * 0.70710678f));
                        Cb[(long)row * M + colb] = __float2bfloat16(v);
                    } else if (EPI == 5) {
                        if (colb < 66) {
                            int hd = colb / 22, jj = colb - hd * 22;
                            Cf[(long)hd * (NTOK * 22) + (long)row * 22 + jj] = v;
                        }
                    } else if (EPI == 6) {
                        __hip_bfloat16* dst = (colb < 256) ? Cb : Ck;
                        int cc = (colb < 256) ? colb : colb - 256;
                        dst[(long)row * 256 + cc] = __float2bfloat16(v);
                    }
                }
            }
        }
    }
}

// ---------------------------------------------------------------- wide GEMM + residual + LN
// C = A[N,K] @ Bw[256,K]^T + bias; x += C; nrm = LN(x; lng,lnb)
// TM=32 rows/block, full 256-wide, 4 waves side by side.
__global__ __launch_bounds__(256) void mm_wide_ln_kernel(
    const __hip_bfloat16* __restrict__ A, const __hip_bfloat16* __restrict__ Bw,
    const float* __restrict__ bias, float* __restrict__ xio,
    __hip_bfloat16* __restrict__ nrm, const float* __restrict__ lng,
    const float* __restrict__ lnb, int K)
{
    constexpr int BK = 64;
    __shared__ __align__(16) short As[32 * BK];
    __shared__ __align__(16) short Bs[256 * BK];
    __shared__ float2 red2[4][32];
    const int tid = threadIdx.x;
    const int lane = tid & 63, wid = tid >> 6;
    const int l15 = lane & 15, g = lane >> 4;
    const int n0 = blockIdx.x * 32;
    f32x4 acc[2][4] = {};

    for (int k0 = 0; k0 < K; k0 += BK) {
        __syncthreads();
        {
            int r = tid >> 3, sl = tid & 7, ss = sl ^ (r & 7);
            gl_lds16(A + (long)(n0 + r) * K + k0 + ss * 8, (char*)As + tid * 16);
        }
        #pragma unroll
        for (int j = 0; j < 8; ++j) {
            int cid = tid + j * 256;
            int r = cid >> 3, sl = cid & 7, ss = sl ^ (r & 7);
            gl_lds16(Bw + (long)r * K + k0 + ss * 8, (char*)Bs + cid * 16);
        }
        __syncthreads();
        #pragma unroll
        for (int ks = 0; ks < 2; ++ks) {
            short8v af[2], bfr[4];
            #pragma unroll
            for (int mi = 0; mi < 2; ++mi) {
                int row = mi * 16 + l15;
                int slot = (ks * 4 + g) ^ (row & 7);
                af[mi] = *(const short8v*)((const char*)As + row * (BK * 2) + slot * 16);
            }
            #pragma unroll
            for (int ni = 0; ni < 4; ++ni) {
                int brow = wid * 64 + ni * 16 + l15;
                int slot = (ks * 4 + g) ^ (brow & 7);
                bfr[ni] = *(const short8v*)((const char*)Bs + brow * (BK * 2) + slot * 16);
            }
            #pragma unroll
            for (int mi = 0; mi < 2; ++mi)
                #pragma unroll
                for (int ni = 0; ni < 4; ++ni)
                    acc[mi][ni] = __builtin_amdgcn_mfma_f32_16x16x32_bf16(
                        af[mi], bfr[ni], acc[mi][ni], 0, 0, 0);
        }
    }

    // residual add + row stats
    float pvt[2][4][4];
    float rs[2][4], rq[2][4];
    #pragma unroll
    for (int mi = 0; mi < 2; ++mi)
        #pragma unroll
        for (int i = 0; i < 4; ++i) { rs[mi][i] = 0.f; rq[mi][i] = 0.f; }
    #pragma unroll
    for (int mi = 0; mi < 2; ++mi) {
        #pragma unroll
        for (int ni = 0; ni < 4; ++ni) {
            int col = wid * 64 + ni * 16 + l15;
            float bv = bias[col];
            #pragma unroll
            for (int i = 0; i < 4; ++i) {
                int row = n0 + mi * 16 + g * 4 + i;
                float v = acc[mi][ni][i] + bv + xio[(long)row * 256 + col];
                pvt[mi][ni][i] = v;
                rs[mi][i] += v;
                rq[mi][i] += v * v;
            }
        }
    }
    #pragma unroll
    for (int mi = 0; mi < 2; ++mi)
        #pragma unroll
        for (int i = 0; i < 4; ++i) {
            #pragma unroll
            for (int off = 8; off; off >>= 1) {
                rs[mi][i] += __shfl_xor(rs[mi][i], off);
                rq[mi][i] += __shfl_xor(rq[mi][i], off);
            }
        }
    __syncthreads();
    if (l15 == 0) {
        #pragma unroll
        for (int mi = 0; mi < 2; ++mi)
            #pragma unroll
            for (int i = 0; i < 4; ++i)
                red2[wid][mi * 16 + g * 4 + i] = make_float2(rs[mi][i], rq[mi][i]);
    }
    __syncthreads();
    #pragma unroll
    for (int mi = 0; mi < 2; ++mi) {
        #pragma unroll
        for (int i = 0; i < 4; ++i) {
            int lr = mi * 16 + g * 4 + i;
            float s1 = red2[0][lr].x + red2[1][lr].x + red2[2][lr].x + red2[3][lr].x;
            float s2 = red2[0][lr].y + red2[1][lr].y + red2[2][lr].y + red2[3][lr].y;
            float mean = s1 * (1.f / 256.f);
            float var = s2 * (1.f / 256.f) - mean * mean;
            float rsx = rsqrtf(var + 1e-5f);
            int row = n0 + lr;
            #pragma unroll
            for (int ni = 0; ni < 4; ++ni) {
                int col = wid * 64 + ni * 16 + l15;
                float v = pvt[mi][ni][i];
                xio[(long)row * 256 + col] = v;
                nrm[(long)row * 256 + col] =
                    __float2bfloat16((v - mean) * rsx * lng[col] + lnb[col]);
            }
        }
    }
}

// ---------------------------------------------------------------- MFMA flash attention
__global__ __launch_bounds__(256) void attn_mfma_kernel(
    const __hip_bfloat16* __restrict__ Q, const __hip_bfloat16* __restrict__ Kx,
    const __hip_bfloat16* __restrict__ Vt, __hip_bfloat16* __restrict__ Oa,
    const float* __restrict__ dsc, const float* __restrict__ dss)
{
    __shared__ __align__(16) short Qs[64 * 32];
    __shared__ __align__(16) short Ks[64 * 32];
    __shared__ __align__(16) short Vs[32 * 64];
    __shared__ __align__(16) short Ps[4 * 16 * 64];
    const int tid = threadIdx.x, lane = tid & 63, wid = tid >> 6;
    const int qt = blockIdx.x, bh = blockIdx.y, b = bh >> 3, h = bh & 7;
    const float pen = fabsf(dsc[h] * (1.f - 0.5f * dss[h]));
    const int l15 = lane & 15, g = lane >> 4;
    const float scale = 0.17677669529663689f;

    {
        int r = tid >> 2, sl = tid & 3, ss = sl ^ (r & 3);
        gl_lds16(Q + ((long)(b * SEQ + qt * 64 + r) * DMODEL + h * 32) + ss * 8,
                 (char*)Qs + tid * 16);
    }
    float mrow[4], lrow[4];
    #pragma unroll
    for (int i = 0; i < 4; ++i) { mrow[i] = -1e30f; lrow[i] = 0.f; }
    f32x4 oacc[2] = {};
    float qpos[4];
    #pragma unroll
    for (int i = 0; i < 4; ++i) qpos[i] = (float)(qt * 64 + wid * 16 + g * 4 + i);

    for (int kt = 0; kt < 16; ++kt) {
        {
            int r = tid >> 2, sl = tid & 3, ss = sl ^ (r & 3);
            gl_lds16(Kx + ((long)(b * SEQ + kt * 64 + r) * DMODEL + h * 32) + ss * 8,
                     (char*)Ks + tid * 16);
            int d = tid >> 3, sl8 = tid & 7, ss8 = sl8 ^ (d & 7);
            gl_lds16(Vt + ((long)(bh * 32 + d) << 10) + kt * 64 + ss8 * 8,
                     (char*)Vs + tid * 16);
        }
        __syncthreads();

        short8v aq;
        {
            int row = wid * 16 + l15;
            int slot = g ^ (row & 3);
            aq = *(const short8v*)((const char*)Qs + row * 64 + slot * 16);
        }
        f32x4 sa[4];
        #pragma unroll
        for (int ni = 0; ni < 4; ++ni) {
            int krow = ni * 16 + l15;
            int slot = g ^ (krow & 3);
            short8v bk = *(const short8v*)((const char*)Ks + krow * 64 + slot * 16);
            f32x4 z = {0.f, 0.f, 0.f, 0.f};
            sa[ni] = __builtin_amdgcn_mfma_f32_16x16x32_bf16(aq, bk, z, 0, 0, 0);
        }
        float sc[4][4], tmax[4];
        #pragma unroll
        for (int i = 0; i < 4; ++i) tmax[i] = -1e30f;
        #pragma unroll
        for (int ni = 0; ni < 4; ++ni) {
            float kpos = (float)(kt * 64 + ni * 16 + l15);
            #pragma unroll
            for (int i = 0; i < 4; ++i) {
                float v = sa[ni][i] * scale - pen * fabsf(qpos[i] - kpos);
                sc[ni][i] = v;
                tmax[i] = fmaxf(tmax[i], v);
            }
        }
        #pragma unroll
        for (int i = 0; i < 4; ++i) {
            #pragma unroll
            for (int off = 8; off; off >>= 1)
                tmax[i] = fmaxf(tmax[i], __shfl_xor(tmax[i], off));
        }
        float fac[4];
        #pragma unroll
        for (int i = 0; i < 4; ++i) {
            float mn = fmaxf(mrow[i], tmax[i]);
            fac[i] = __expf(mrow[i] - mn);
            mrow[i] = mn;
        }
        float ps[4] = {0.f, 0.f, 0.f, 0.f};
        #pragma unroll
        for (int ni = 0; ni < 4; ++ni) {
            #pragma unroll
            for (int i = 0; i < 4; ++i) {
                float p = __expf(sc[ni][i] - mrow[i]);
                ps[i] += p;
                int lr = g * 4 + i, key = ni * 16 + l15;
                int slot = (key >> 3) ^ (lr & 7);
                *(short*)((char*)Ps + wid * 2048 + lr * 128 + slot * 16 + (key & 7) * 2) = f2bf(p);
            }
        }
        #pragma unroll
        for (int i = 0; i < 4; ++i) {
            #pragma unroll
            for (int off = 8; off; off >>= 1) ps[i] += __shfl_xor(ps[i], off);
            lrow[i] = lrow[i] * fac[i] + ps[i];
        }
        #pragma unroll
        for (int n2 = 0; n2 < 2; ++n2)
            #pragma unroll
            for (int i = 0; i < 4; ++i) oacc[n2][i] *= fac[i];

        #pragma unroll
        for (int ks = 0; ks < 2; ++ks) {
            int lr = l15;
            int slot = (ks * 4 + g) ^ (lr & 7);
            short8v pa = *(const short8v*)((const char*)Ps + wid * 2048 + lr * 128 + slot * 16);
            #pragma unroll
            for (int n2 = 0; n2 < 2; ++n2) {
                int d = n2 * 16 + l15;
                int vslot = (ks * 4 + g) ^ (d & 7);
                short8v vb = *(const short8v*)((const char*)Vs + d * 128 + vslot * 16);
                oacc[n2] = __builtin_amdgcn_mfma_f32_16x16x32_bf16(pa, vb, oacc[n2], 0, 0, 0);
            }
        }
        __syncthreads();
    }
    #pragma unroll
    for (int n2 = 0; n2 < 2; ++n2) {
        #pragma unroll
        for (int i = 0; i < 4; ++i) {
            float v = oacc[n2][i] / lrow[i];
            long row = b * SEQ + qt * 64 + wid * 16 + g * 4 + i;
            Oa[row * DMODEL + h * 32 + n2 * 16 + l15] = __float2bfloat16(v);
        }
    }
}

// ---------------------------------------------------------------- small fused kernels
__global__ __launch_bounds__(256) void gather_kernel(
    const int* __restrict__ roots, const float* __restrict__ letE,
    __hip_bfloat16* __restrict__ cat,
    const float* __restrict__ h1b, const float* __restrict__ h2b,
    const float* __restrict__ h3b, float* __restrict__ biascat)
{
    const int n = blockIdx.x, t = threadIdx.x;
    int r0 = roots[n * 3 + 0], r1 = roots[n * 3 + 1], r2 = roots[n * 3 + 2];
    cat[(long)n * 768 + t]       = __float2bfloat16(letE[r0 * DMODEL + t]);
    cat[(long)n * 768 + 256 + t] = __float2bfloat16(letE[r1 * DMODEL + t]);
    cat[(long)n * 768 + 512 + t] = __float2bfloat16(letE[r2 * DMODEL + t]);
    if (n == 0 && t < 66)
        biascat[t] = (t < 22) ? h1b[t] : (t < 44) ? h2b[t - 22] : h3b[t - 44];
}

__global__ __launch_bounds__(256) void ln_gem_kernel(
    const float* __restrict__ tmpf, const float* __restrict__ gem,
    const float* __restrict__ gg, const float* __restrict__ gb,
    __hip_bfloat16* __restrict__ catin)
{
    __shared__ float red[8];
    const int n = blockIdx.x, t = threadIdx.x;
    const float LC = 0.0359778921f;
    float v = tmpf[(long)n * DMODEL + t];
    float s1 = v, s2 = v * v;
    blockSum2(s1, s2, red);
    float mean = s1 * (1.f / 256.f);
    float var = s2 * (1.f / 256.f) - mean * mean;
    catin[(long)n * 512 + t] =
        __float2bfloat16((v - mean) * rsqrtf(var + 1e-5f) * gg[t] + gb[t]);
    float gv = gem[n];
    int j = (t < 128) ? t : t - 128;
    float ang = gv * 500.f * expf(-(float)(2 * j) * LC);
    catin[(long)n * 512 + 256 + t] = __float2bfloat16((t < 128) ? sinf(ang) : cosf(ang));
}

// x = LN(tmpf + PE; ilg,ilb); nrm = LN(x; g1,b1)  (layer0 pre-attn norm)
__global__ __launch_bounds__(256) void ln_pe2_kernel(
    const float* __restrict__ tmpf, const float* __restrict__ gg,
    const float* __restrict__ gb, const float* __restrict__ g1,
    const float* __restrict__ b1, float* __restrict__ x,
    __hip_bfloat16* __restrict__ nrm)
{
    __shared__ float red[8];
    const int n = blockIdx.x, t = threadIdx.x;
    const int s = n & (SEQ - 1);
    const float LC = 0.0359778921f;
    float pos = (float)(SEQ - 1 - s);
    float dv = expf(-(float)(t & ~1) * LC);
    float pe = (t & 1) ? cosf(pos * dv) : sinf(pos * dv);
    float v = tmpf[(long)n * DMODEL + t] + pe;
    float s1 = v, s2 = v * v;
    blockSum2(s1, s2, red);
    float mean = s1 * (1.f / 256.f);
    float var = s2 * (1.f / 256.f) - mean * mean;
    float xv = (v - mean) * rsqrtf(var + 1e-5f) * gg[t] + gb[t];
    x[(long)n * DMODEL + t] = xv;
    s1 = xv; s2 = xv * xv;
    blockSum2(s1, s2, red);
    mean = s1 * (1.f / 256.f);
    var = s2 * (1.f / 256.f) - mean * mean;
    nrm[(long)n * DMODEL + t] =
        __float2bfloat16((xv - mean) * rsqrtf(var + 1e-5f) * g1[t] + b1[t]);
}

// ---------------------------------------------------------------- launch
extern "C" void kernel_launch(void* const* d_in, const int* in_sizes, int n_in,
                              void* d_out, int out_size, void* d_ws, size_t ws_size,
                              hipStream_t stream)
{
    const int*   roots = (const int*)  d_in[0];
    const float* gem   = (const float*)d_in[1];
    const float* letE  = (const float*)d_in[2];
    const float* rpw   = (const float*)d_in[3];
    const float* rpb   = (const float*)d_in[4];
    const float* rlg   = (const float*)d_in[5];
    const float* rlb   = (const float*)d_in[6];
    const float* ipw   = (const float*)d_in[7];
    const float* ipb   = (const float*)d_in[8];
    const float* ilg   = (const float*)d_in[9];
    const float* ilb   = (const float*)d_in[10];
    const float* qw    = (const float*)d_in[11];
    const float* qb    = (const float*)d_in[12];
    const float* kw    = (const float*)d_in[13];
    const float* kb    = (const float*)d_in[14];
    const float* vw    = (const float*)d_in[15];
    const float* vb    = (const float*)d_in[16];
    const float* ow    = (const float*)d_in[17];
    const float* ob    = (const float*)d_in[18];
    const float* dsc   = (const float*)d_in[19];
    const float* dss   = (const float*)d_in[20];
    const float* ff1w  = (const float*)d_in[21];
    const float* ff1b  = (const float*)d_in[22];
    const float* ff2w  = (const float*)d_in[23];
    const float* ff2b  = (const float*)d_in[24];
    const float* ln1g  = (const float*)d_in[25];
    const float* ln1b  = (const float*)d_in[26];
    const float* ln2g  = (const float*)d_in[27];
    const float* ln2b  = (const float*)d_in[28];
    const float* olng  = (const float*)d_in[29];
    const float* olnb  = (const float*)d_in[30];
    const float* h1w   = (const float*)d_in[31];
    const float* h1b   = (const float*)d_in[32];
    const float* h2w   = (const float*)d_in[33];
    const float* h2b   = (const float*)d_in[34];
    const float* h3w   = (const float*)d_in[35];
    const float* h3b   = (const float*)d_in[36];

    char* wsb = (char*)d_ws;
    float*          x    = (float*)         (wsb + (0l  << 20));
    float*          tmpf = (float*)         (wsb + (4l  << 20));
    __hip_bfloat16* nrm  = (__hip_bfloat16*)(wsb + (8l  << 20));
    __hip_bfloat16* qbuf = (__hip_bfloat16*)(wsb + (10l << 20));
    __hip_bfloat16* kbuf = (__hip_bfloat16*)(wsb + (12l << 20));
    __hip_bfloat16* vtb  = (__hip_bfloat16*)(wsb + (14l << 20));
    __hip_bfloat16* aob  = (__hip_bfloat16*)(wsb + (16l << 20));
    __hip_bfloat16* hbb  = (__hip_bfloat16*)(wsb + (18l << 20));
    __hip_bfloat16* catb  = hbb;     // alias (embed phase only)
    __hip_bfloat16* catin = qbuf;    // alias (embed phase only, spans q+k)
    __hip_bfloat16* wb   = (__hip_bfloat16*)(wsb + (26l << 20));
    float*          biascat = (float*)      (wsb + (34l << 20));

    __hip_bfloat16* rpw_t  = wb;
    __hip_bfloat16* ipw_t  = wb + 196608;
    __hip_bfloat16* qkv_t  = wb + 327680;   // per layer: [768][256] (q|k|v)
    __hip_bfloat16* ow_t   = wb + 1114112;
    __hip_bfloat16* ff1w_t = wb + 1376256;
    __hip_bfloat16* ff2w_t = wb + 2424832;
    __hip_bfloat16* head_t = wb + 3473408;

    hipMemsetAsync(head_t, 0, 32768 * 2, stream);

    TDs td;
    td.d[0] = {rpw, rpw_t, 768, 256};
    td.d[1] = {ipw, ipw_t, 512, 256};
    for (int l = 0; l < 4; ++l) {
        td.d[2 + l]  = {qw + l * 65536,  qkv_t + l * 196608 + 0,      256, 256};
        td.d[6 + l]  = {kw + l * 65536,  qkv_t + l * 196608 + 65536,  256, 256};
        td.d[10 + l] = {vw + l * 65536,  qkv_t + l * 196608 + 131072, 256, 256};
        td.d[14 + l] = {ow + l * 65536,  ow_t + l * 65536,  256, 256};
        td.d[18 + l] = {ff1w + l * 262144, ff1w_t + l * 262144, 256, 1024};
        td.d[22 + l] = {ff2w + l * 262144, ff2w_t + l * 262144, 1024, 256};
    }
    td.d[26] = {h1w, head_t + 0 * 22 * 256, 256, 22};
    td.d[27] = {h2w, head_t + 1 * 22 * 256, 256, 22};
    td.d[28] = {h3w, head_t + 2 * 22 * 256, 256, 22};
    transpose_kernel<<<dim3(256, 29), 256, 0, stream>>>(td);

    gather_kernel<<<NTOK, 256, 0, stream>>>(roots, letE, catb, h1b, h2b, h3b, biascat);
    mm_kernel<64, 64, 0><<<dim3(4, 64), 256, 0, stream>>>(
        catb, rpw_t, rpb, tmpf, nullptr, NTOK, 768, 256, nullptr, nullptr, nullptr, nullptr);
    ln_gem_kernel<<<NTOK, 256, 0, stream>>>(tmpf, gem, rlg, rlb, catin);
    mm_kernel<64, 64, 0><<<dim3(4, 64), 256, 0, stream>>>(
        catin, ipw_t, ipb, tmpf, nullptr, NTOK, 512, 256, nullptr, nullptr, nullptr, nullptr);
    ln_pe2_kernel<<<NTOK, 256, 0, stream>>>(tmpf, ilg, ilb, ln1g, ln1b, x, nrm);

    for (int l = 0; l < NLAYER; ++l) {
        mm_kernel<64, 64, 6><<<dim3(12, 64), 256, 0, stream>>>(
            nrm, qkv_t + l * 196608, qb + l * 256, nullptr, qbuf, NTOK, 256, 768,
            kb + l * 256, vb + l * 256, kbuf, vtb);
        attn_mfma_kernel<<<dim3(16, 32), 256, 0, stream>>>(qbuf, kbuf, vtb, aob,
                                                           dsc + l * 8, dss + l * 8);
        mm_wide_ln_kernel<<<dim3(NTOK / 32), 256, 0, stream>>>(
            aob, ow_t + l * 65536, ob + l * 256, x, nrm,
            ln2g + l * 256, ln2b + l * 256, 256);
        mm_kernel<128, 128, 2><<<dim3(8, 32), 256, 0, stream>>>(
            nrm, ff1w_t + l * 262144, ff1b + l * 1024, nullptr, hbb, NTOK, 256, 1024,
            nullptr, nullptr, nullptr, nullptr);
        const float* ng = (l == 3) ? olng : ln1g + (l + 1) * 256;
        const float* nb = (l == 3) ? olnb : ln1b + (l + 1) * 256;
        mm_wide_ln_kernel<<<dim3(NTOK / 32), 256, 0, stream>>>(
            hbb, ff2w_t + l * 262144, ff2b + l * 256, x, nrm, ng, nb, 1024);
    }
    mm_kernel<64, 64, 5><<<dim3(2, 64), 256, 0, stream>>>(
        nrm, head_t, biascat, (float*)d_out, nullptr, NTOK, 256, 128,
        nullptr, nullptr, nullptr, nullptr);
}

// Round 4
// 472.162 us; speedup vs baseline: 3.0215x; 1.1132x over previous
//
#include <hip/hip_runtime.h>
#include <hip/hip_bf16.h>
#include <math.h>

#define NTOK   4096
#define SEQ    1024
#define DMODEL 256
#define NHEAD  8
#define FDIM   1024
#define NLAYER 4

typedef __attribute__((ext_vector_type(8))) short short8v;
typedef __attribute__((ext_vector_type(4))) float f32x4;

#define LDS3(p) ((__attribute__((address_space(3))) unsigned int*)(p))
#define GAS1(p) ((const __attribute__((address_space(1))) unsigned int*)(p))

__device__ __forceinline__ void gl_lds16(const void* g, void* l) {
    __builtin_amdgcn_global_load_lds(GAS1(g), LDS3(l), 16, 0, 0);
}
__device__ __forceinline__ short f2bf(float v) {
    __hip_bfloat16 h = __float2bfloat16(v);
    return __builtin_bit_cast(short, h);
}

// ---------------------------------------------------------------- reductions
__device__ __forceinline__ void blockSum2(float& s1, float& s2, float* red) {
    #pragma unroll
    for (int off = 32; off > 0; off >>= 1) {
        s1 += __shfl_down(s1, off);
        s2 += __shfl_down(s2, off);
    }
    int lane = threadIdx.x & 63, w = threadIdx.x >> 6;
    __syncthreads();
    if (lane == 0) { red[w] = s1; red[4 + w] = s2; }
    __syncthreads();
    s1 = red[0] + red[1] + red[2] + red[3];
    s2 = red[4] + red[5] + red[6] + red[7];
}

// ---------------------------------------------------------------- weight transpose fp32[K][M] -> bf16[M][K]
struct TD { const float* src; __hip_bfloat16* dst; int K; int M; };
struct TDs { TD d[29]; };

__global__ __launch_bounds__(256) void transpose_kernel(TDs p) {
    __shared__ float ld[32][33];
    TD d = p.d[blockIdx.y];
    int tm = (d.M + 31) >> 5;
    int kt = blockIdx.x / tm, mt = blockIdx.x % tm;
    if (kt * 32 >= d.K) return;
    int tx = threadIdx.x & 31, ty = threadIdx.x >> 5;
    #pragma unroll
    for (int r = 0; r < 4; ++r) {
        int k = kt * 32 + ty + r * 8, m = mt * 32 + tx;
        if (m < d.M) ld[ty + r * 8][tx] = d.src[(long)k * d.M + m];
    }
    __syncthreads();
    #pragma unroll
    for (int r = 0; r < 4; ++r) {
        int m = mt * 32 + ty + r * 8, k = kt * 32 + tx;
        if (m < d.M) d.dst[(long)m * d.K + k] = __float2bfloat16(ld[tx][ty + r * 8]);
    }
}

// ---------------------------------------------------------------- MFMA GEMM (generic tile)
// EPI 0: fp32 store | 2: gelu->bf16 | 5: heads scatter (cols<66) | 6: QKV split
template <int TM, int TN, int EPI>
__global__ __launch_bounds__(256) void mm_kernel(
    const __hip_bfloat16* __restrict__ A, const __hip_bfloat16* __restrict__ Bw,
    const float* __restrict__ bias, float* __restrict__ Cf,
    __hip_bfloat16* __restrict__ Cb, int N, int K, int M,
    const float* __restrict__ b2, const float* __restrict__ b3,
    __hip_bfloat16* __restrict__ Ck, __hip_bfloat16* __restrict__ Cv)
{
    constexpr int BK = 64;
    __shared__ __align__(16) short As[TM * BK];
    __shared__ __align__(16) short Bs[TN * BK];
    const int tid = threadIdx.x;
    const int lane = tid & 63, wid = tid >> 6;
    const int wr = wid >> 1, wc = wid & 1;
    const int n0 = blockIdx.y * TM, m0 = blockIdx.x * TN;
    const int l15 = lane & 15, g = lane >> 4;
    constexpr int FM = (TM / 32 > 0) ? TM / 32 : 1;
    constexpr int FN = TN / 32;
    f32x4 acc[FM][FN] = {};

    for (int k0 = 0; k0 < K; k0 += BK) {
        constexpr int CA = TM * 8;
        __syncthreads();
        #pragma unroll
        for (int j = 0; j < (CA + 255) / 256; ++j) {
            int cid = tid + j * 256;
            if (CA % 256 == 0 || cid < CA) {
                int r = cid >> 3, sl = cid & 7, ss = sl ^ (r & 7);
                gl_lds16(A + (long)(n0 + r) * K + k0 + ss * 8, (char*)As + cid * 16);
            }
        }
        constexpr int CB = TN * 8;
        #pragma unroll
        for (int j = 0; j < CB / 256; ++j) {
            int cid = tid + j * 256;
            int r = cid >> 3, sl = cid & 7, ss = sl ^ (r & 7);
            gl_lds16(Bw + (long)(m0 + r) * K + k0 + ss * 8, (char*)Bs + cid * 16);
        }
        __syncthreads();
        #pragma unroll
        for (int ks = 0; ks < 2; ++ks) {
            short8v af[FM], bfr[FN];
            #pragma unroll
            for (int mi = 0; mi < FM; ++mi) {
                int row = wr * (TM / 2) + mi * 16 + l15;
                int slot = (ks * 4 + g) ^ (row & 7);
                af[mi] = *(const short8v*)((const char*)As + row * (BK * 2) + slot * 16);
            }
            #pragma unroll
            for (int ni = 0; ni < FN; ++ni) {
                int row = wc * (TN / 2) + ni * 16 + l15;
                int slot = (ks * 4 + g) ^ (row & 7);
                bfr[ni] = *(const short8v*)((const char*)Bs + row * (BK * 2) + slot * 16);
            }
            #pragma unroll
            for (int mi = 0; mi < FM; ++mi)
                #pragma unroll
                for (int ni = 0; ni < FN; ++ni)
                    acc[mi][ni] = __builtin_amdgcn_mfma_f32_16x16x32_bf16(
                        af[mi], bfr[ni], acc[mi][ni], 0, 0, 0);
        }
    }

    #pragma unroll
    for (int mi = 0; mi < FM; ++mi) {
        #pragma unroll
        for (int ni = 0; ni < FN; ++ni) {
            int colb = m0 + wc * (TN / 2) + ni * 16 + l15;
            float bv;
            if (EPI == 6) bv = (colb < 256) ? bias[colb] : (colb < 512) ? b2[colb - 256] : b3[colb - 512];
            else bv = bias[colb];
            if (EPI == 6 && colb >= 512) {
                int c2 = colb - 512;
                int h = c2 >> 5, dd = c2 & 31;
                int row0 = n0 + wr * (TM / 2) + mi * 16 + g * 4;
                int bb = row0 >> 10, ss = row0 & 1023;
                short4 pk;
                pk.x = f2bf(acc[mi][ni][0] + bv);
                pk.y = f2bf(acc[mi][ni][1] + bv);
                pk.z = f2bf(acc[mi][ni][2] + bv);
                pk.w = f2bf(acc[mi][ni][3] + bv);
                *(short4*)((short*)Cv + ((long)((bb * 8 + h) * 32 + dd) << 10) + ss) = pk;
            } else {
                #pragma unroll
                for (int i = 0; i < 4; ++i) {
                    int row = n0 + wr * (TM / 2) + mi * 16 + g * 4 + i;
                    float v = acc[mi][ni][i] + bv;
                    if (EPI == 0) Cf[(long)row * M + colb] = v;
                    else if (EPI == 2) {
                        v = 0.5f * v * (1.f + erff(v * 0.70710678f));
                        Cb[(long)row * M + colb] = __float2bfloat16(v);
                    } else if (EPI == 5) {
                        if (colb < 66) {
                            int hd = colb / 22, jj = colb - hd * 22;
                            Cf[(long)hd * (NTOK * 22) + (long)row * 22 + jj] = v;
                        }
                    } else if (EPI == 6) {
                        __hip_bfloat16* dst = (colb < 256) ? Cb : Ck;
                        int cc = (colb < 256) ? colb : colb - 256;
                        dst[(long)row * 256 + cc] = __float2bfloat16(v);
                    }
                }
            }
        }
    }
}

// ---------------------------------------------------------------- wide GEMM + residual + LN
// TM=16 rows/block (grid 256), full 256-wide, 4 waves side by side.
// C = A[N,K] @ Bw[256,K]^T + bias; x += C; nrm = LN(x; lng,lnb)
__global__ __launch_bounds__(256) void mm_wide_ln_kernel(
    const __hip_bfloat16* __restrict__ A, const __hip_bfloat16* __restrict__ Bw,
    const float* __restrict__ bias, float* __restrict__ xio,
    __hip_bfloat16* __restrict__ nrm, const float* __restrict__ lng,
    const float* __restrict__ lnb, int K)
{
    constexpr int BK = 64;
    __shared__ __align__(16) short As[16 * BK];
    __shared__ __align__(16) short Bs[256 * BK];
    __shared__ float2 red2[4][16];
    const int tid = threadIdx.x;
    const int lane = tid & 63, wid = tid >> 6;
    const int l15 = lane & 15, g = lane >> 4;
    const int n0 = blockIdx.x * 16;
    f32x4 acc[4] = {};

    for (int k0 = 0; k0 < K; k0 += BK) {
        __syncthreads();
        if (tid < 128) {
            int r = tid >> 3, sl = tid & 7, ss = sl ^ (r & 7);
            gl_lds16(A + (long)(n0 + r) * K + k0 + ss * 8, (char*)As + tid * 16);
        }
        #pragma unroll
        for (int j = 0; j < 8; ++j) {
            int cid = tid + j * 256;
            int r = cid >> 3, sl = cid & 7, ss = sl ^ (r & 7);
            gl_lds16(Bw + (long)r * K + k0 + ss * 8, (char*)Bs + cid * 16);
        }
        __syncthreads();
        #pragma unroll
        for (int ks = 0; ks < 2; ++ks) {
            short8v af;
            {
                int slot = (ks * 4 + g) ^ (l15 & 7);
                af = *(const short8v*)((const char*)As + l15 * (BK * 2) + slot * 16);
            }
            #pragma unroll
            for (int ni = 0; ni < 4; ++ni) {
                int brow = wid * 64 + ni * 16 + l15;
                int slot = (ks * 4 + g) ^ (brow & 7);
                short8v bfr = *(const short8v*)((const char*)Bs + brow * (BK * 2) + slot * 16);
                acc[ni] = __builtin_amdgcn_mfma_f32_16x16x32_bf16(af, bfr, acc[ni], 0, 0, 0);
            }
        }
    }

    // residual add + row stats (rows n0 + g*4 + i)
    float pvt[4][4];
    float rs[4] = {0.f, 0.f, 0.f, 0.f}, rq[4] = {0.f, 0.f, 0.f, 0.f};
    #pragma unroll
    for (int ni = 0; ni < 4; ++ni) {
        int col = wid * 64 + ni * 16 + l15;
        float bv = bias[col];
        #pragma unroll
        for (int i = 0; i < 4; ++i) {
            int row = n0 + g * 4 + i;
            float v = acc[ni][i] + bv + xio[(long)row * 256 + col];
            pvt[ni][i] = v;
            rs[i] += v;
            rq[i] += v * v;
        }
    }
    #pragma unroll
    for (int i = 0; i < 4; ++i) {
        #pragma unroll
        for (int off = 8; off; off >>= 1) {
            rs[i] += __shfl_xor(rs[i], off);
            rq[i] += __shfl_xor(rq[i], off);
        }
    }
    __syncthreads();
    if (l15 == 0) {
        #pragma unroll
        for (int i = 0; i < 4; ++i)
            red2[wid][g * 4 + i] = make_float2(rs[i], rq[i]);
    }
    __syncthreads();
    #pragma unroll
    for (int i = 0; i < 4; ++i) {
        int lr = g * 4 + i;
        float s1 = red2[0][lr].x + red2[1][lr].x + red2[2][lr].x + red2[3][lr].x;
        float s2 = red2[0][lr].y + red2[1][lr].y + red2[2][lr].y + red2[3][lr].y;
        float mean = s1 * (1.f / 256.f);
        float var = s2 * (1.f / 256.f) - mean * mean;
        float rsx = rsqrtf(var + 1e-5f);
        int row = n0 + lr;
        #pragma unroll
        for (int ni = 0; ni < 4; ++ni) {
            int col = wid * 64 + ni * 16 + l15;
            float v = pvt[ni][i];
            xio[(long)row * 256 + col] = v;
            nrm[(long)row * 256 + col] =
                __float2bfloat16((v - mean) * rsx * lng[col] + lnb[col]);
        }
    }
}

// ---------------------------------------------------------------- MFMA flash attention
__global__ __launch_bounds__(256) void attn_mfma_kernel(
    const __hip_bfloat16* __restrict__ Q, const __hip_bfloat16* __restrict__ Kx,
    const __hip_bfloat16* __restrict__ Vt, __hip_bfloat16* __restrict__ Oa,
    const float* __restrict__ dsc, const float* __restrict__ dss)
{
    __shared__ __align__(16) short Qs[64 * 32];
    __shared__ __align__(16) short Ks[64 * 32];
    __shared__ __align__(16) short Vs[32 * 64];
    __shared__ __align__(16) short Ps[4 * 16 * 64];
    const int tid = threadIdx.x, lane = tid & 63, wid = tid >> 6;
    const int qt = blockIdx.x, bh = blockIdx.y, b = bh >> 3, h = bh & 7;
    const float pen = fabsf(dsc[h] * (1.f - 0.5f * dss[h]));
    const int l15 = lane & 15, g = lane >> 4;
    const float scale = 0.17677669529663689f;

    {
        int r = tid >> 2, sl = tid & 3, ss = sl ^ (r & 3);
        gl_lds16(Q + ((long)(b * SEQ + qt * 64 + r) * DMODEL + h * 32) + ss * 8,
                 (char*)Qs + tid * 16);
    }
    float mrow[4], lrow[4];
    #pragma unroll
    for (int i = 0; i < 4; ++i) { mrow[i] = -1e30f; lrow[i] = 0.f; }
    f32x4 oacc[2] = {};
    float qpos[4];
    #pragma unroll
    for (int i = 0; i < 4; ++i) qpos[i] = (float)(qt * 64 + wid * 16 + g * 4 + i);

    for (int kt = 0; kt < 16; ++kt) {
        {
            int r = tid >> 2, sl = tid & 3, ss = sl ^ (r & 3);
            gl_lds16(Kx + ((long)(b * SEQ + kt * 64 + r) * DMODEL + h * 32) + ss * 8,
                     (char*)Ks + tid * 16);
            int d = tid >> 3, sl8 = tid & 7, ss8 = sl8 ^ (d & 7);
            gl_lds16(Vt + ((long)(bh * 32 + d) << 10) + kt * 64 + ss8 * 8,
                     (char*)Vs + tid * 16);
        }
        __syncthreads();

        short8v aq;
        {
            int row = wid * 16 + l15;
            int slot = g ^ (row & 3);
            aq = *(const short8v*)((const char*)Qs + row * 64 + slot * 16);
        }
        f32x4 sa[4];
        #pragma unroll
        for (int ni = 0; ni < 4; ++ni) {
            int krow = ni * 16 + l15;
            int slot = g ^ (krow & 3);
            short8v bk = *(const short8v*)((const char*)Ks + krow * 64 + slot * 16);
            f32x4 z = {0.f, 0.f, 0.f, 0.f};
            sa[ni] = __builtin_amdgcn_mfma_f32_16x16x32_bf16(aq, bk, z, 0, 0, 0);
        }
        float sc[4][4], tmax[4];
        #pragma unroll
        for (int i = 0; i < 4; ++i) tmax[i] = -1e30f;
        #pragma unroll
        for (int ni = 0; ni < 4; ++ni) {
            float kpos = (float)(kt * 64 + ni * 16 + l15);
            #pragma unroll
            for (int i = 0; i < 4; ++i) {
                float v = sa[ni][i] * scale - pen * fabsf(qpos[i] - kpos);
                sc[ni][i] = v;
                tmax[i] = fmaxf(tmax[i], v);
            }
        }
        #pragma unroll
        for (int i = 0; i < 4; ++i) {
            #pragma unroll
            for (int off = 8; off; off >>= 1)
                tmax[i] = fmaxf(tmax[i], __shfl_xor(tmax[i], off));
        }
        float fac[4];
        #pragma unroll
        for (int i = 0; i < 4; ++i) {
            float mn = fmaxf(mrow[i], tmax[i]);
            fac[i] = __expf(mrow[i] - mn);
            mrow[i] = mn;
        }
        float ps[4] = {0.f, 0.f, 0.f, 0.f};
        #pragma unroll
        for (int ni = 0; ni < 4; ++ni) {
            #pragma unroll
            for (int i = 0; i < 4; ++i) {
                float p = __expf(sc[ni][i] - mrow[i]);
                ps[i] += p;
                int lr = g * 4 + i, key = ni * 16 + l15;
                int slot = (key >> 3) ^ (lr & 7);
                *(short*)((char*)Ps + wid * 2048 + lr * 128 + slot * 16 + (key & 7) * 2) = f2bf(p);
            }
        }
        #pragma unroll
        for (int i = 0; i < 4; ++i) {
            #pragma unroll
            for (int off = 8; off; off >>= 1) ps[i] += __shfl_xor(ps[i], off);
            lrow[i] = lrow[i] * fac[i] + ps[i];
        }
        #pragma unroll
        for (int n2 = 0; n2 < 2; ++n2)
            #pragma unroll
            for (int i = 0; i < 4; ++i) oacc[n2][i] *= fac[i];

        #pragma unroll
        for (int ks = 0; ks < 2; ++ks) {
            int lr = l15;
            int slot = (ks * 4 + g) ^ (lr & 7);
            short8v pa = *(const short8v*)((const char*)Ps + wid * 2048 + lr * 128 + slot * 16);
            #pragma unroll
            for (int n2 = 0; n2 < 2; ++n2) {
                int d = n2 * 16 + l15;
                int vslot = (ks * 4 + g) ^ (d & 7);
                short8v vb = *(const short8v*)((const char*)Vs + d * 128 + vslot * 16);
                oacc[n2] = __builtin_amdgcn_mfma_f32_16x16x32_bf16(pa, vb, oacc[n2], 0, 0, 0);
            }
        }
        __syncthreads();
    }
    #pragma unroll
    for (int n2 = 0; n2 < 2; ++n2) {
        #pragma unroll
        for (int i = 0; i < 4; ++i) {
            float v = oacc[n2][i] / lrow[i];
            long row = b * SEQ + qt * 64 + wid * 16 + g * 4 + i;
            Oa[row * DMODEL + h * 32 + n2 * 16 + l15] = __float2bfloat16(v);
        }
    }
}

// ---------------------------------------------------------------- small fused kernels
__global__ __launch_bounds__(256) void gather_kernel(
    const int* __restrict__ roots, const float* __restrict__ letE,
    __hip_bfloat16* __restrict__ cat,
    const float* __restrict__ h1b, const float* __restrict__ h2b,
    const float* __restrict__ h3b, float* __restrict__ biascat)
{
    const int n = blockIdx.x, t = threadIdx.x;
    int r0 = roots[n * 3 + 0], r1 = roots[n * 3 + 1], r2 = roots[n * 3 + 2];
    cat[(long)n * 768 + t]       = __float2bfloat16(letE[r0 * DMODEL + t]);
    cat[(long)n * 768 + 256 + t] = __float2bfloat16(letE[r1 * DMODEL + t]);
    cat[(long)n * 768 + 512 + t] = __float2bfloat16(letE[r2 * DMODEL + t]);
    if (n == 0 && t < 66)
        biascat[t] = (t < 22) ? h1b[t] : (t < 44) ? h2b[t - 22] : h3b[t - 44];
}

__global__ __launch_bounds__(256) void ln_gem_kernel(
    const float* __restrict__ tmpf, const float* __restrict__ gem,
    const float* __restrict__ gg, const float* __restrict__ gb,
    __hip_bfloat16* __restrict__ catin)
{
    __shared__ float red[8];
    const int n = blockIdx.x, t = threadIdx.x;
    const float LC = 0.0359778921f;
    float v = tmpf[(long)n * DMODEL + t];
    float s1 = v, s2 = v * v;
    blockSum2(s1, s2, red);
    float mean = s1 * (1.f / 256.f);
    float var = s2 * (1.f / 256.f) - mean * mean;
    catin[(long)n * 512 + t] =
        __float2bfloat16((v - mean) * rsqrtf(var + 1e-5f) * gg[t] + gb[t]);
    float gv = gem[n];
    int j = (t < 128) ? t : t - 128;
    float ang = gv * 500.f * expf(-(float)(2 * j) * LC);
    catin[(long)n * 512 + 256 + t] = __float2bfloat16((t < 128) ? sinf(ang) : cosf(ang));
}

// x = LN(tmpf + PE; ilg,ilb); nrm = LN(x; g1,b1)  (layer0 pre-attn norm)
__global__ __launch_bounds__(256) void ln_pe2_kernel(
    const float* __restrict__ tmpf, const float* __restrict__ gg,
    const float* __restrict__ gb, const float* __restrict__ g1,
    const float* __restrict__ b1, float* __restrict__ x,
    __hip_bfloat16* __restrict__ nrm)
{
    __shared__ float red[8];
    const int n = blockIdx.x, t = threadIdx.x;
    const int s = n & (SEQ - 1);
    const float LC = 0.0359778921f;
    float pos = (float)(SEQ - 1 - s);
    float dv = expf(-(float)(t & ~1) * LC);
    float pe = (t & 1) ? cosf(pos * dv) : sinf(pos * dv);
    float v = tmpf[(long)n * DMODEL + t] + pe;
    float s1 = v, s2 = v * v;
    blockSum2(s1, s2, red);
    float mean = s1 * (1.f / 256.f);
    float var = s2 * (1.f / 256.f) - mean * mean;
    float xv = (v - mean) * rsqrtf(var + 1e-5f) * gg[t] + gb[t];
    x[(long)n * DMODEL + t] = xv;
    s1 = xv; s2 = xv * xv;
    blockSum2(s1, s2, red);
    mean = s1 * (1.f / 256.f);
    var = s2 * (1.f / 256.f) - mean * mean;
    nrm[(long)n * DMODEL + t] =
        __float2bfloat16((xv - mean) * rsqrtf(var + 1e-5f) * g1[t] + b1[t]);
}

// ---------------------------------------------------------------- launch
extern "C" void kernel_launch(void* const* d_in, const int* in_sizes, int n_in,
                              void* d_out, int out_size, void* d_ws, size_t ws_size,
                              hipStream_t stream)
{
    const int*   roots = (const int*)  d_in[0];
    const float* gem   = (const float*)d_in[1];
    const float* letE  = (const float*)d_in[2];
    const float* rpw   = (const float*)d_in[3];
    const float* rpb   = (const float*)d_in[4];
    const float* rlg   = (const float*)d_in[5];
    const float* rlb   = (const float*)d_in[6];
    const float* ipw   = (const float*)d_in[7];
    const float* ipb   = (const float*)d_in[8];
    const float* ilg   = (const float*)d_in[9];
    const float* ilb   = (const float*)d_in[10];
    const float* qw    = (const float*)d_in[11];
    const float* qb    = (const float*)d_in[12];
    const float* kw    = (const float*)d_in[13];
    const float* kb    = (const float*)d_in[14];
    const float* vw    = (const float*)d_in[15];
    const float* vb    = (const float*)d_in[16];
    const float* ow    = (const float*)d_in[17];
    const float* ob    = (const float*)d_in[18];
    const float* dsc   = (const float*)d_in[19];
    const float* dss   = (const float*)d_in[20];
    const float* ff1w  = (const float*)d_in[21];
    const float* ff1b  = (const float*)d_in[22];
    const float* ff2w  = (const float*)d_in[23];
    const float* ff2b  = (const float*)d_in[24];
    const float* ln1g  = (const float*)d_in[25];
    const float* ln1b  = (const float*)d_in[26];
    const float* ln2g  = (const float*)d_in[27];
    const float* ln2b  = (const float*)d_in[28];
    const float* olng  = (const float*)d_in[29];
    const float* olnb  = (const float*)d_in[30];
    const float* h1w   = (const float*)d_in[31];
    const float* h1b   = (const float*)d_in[32];
    const float* h2w   = (const float*)d_in[33];
    const float* h2b   = (const float*)d_in[34];
    const float* h3w   = (const float*)d_in[35];
    const float* h3b   = (const float*)d_in[36];

    char* wsb = (char*)d_ws;
    float*          x    = (float*)         (wsb + (0l  << 20));
    float*          tmpf = (float*)         (wsb + (4l  << 20));
    __hip_bfloat16* nrm  = (__hip_bfloat16*)(wsb + (8l  << 20));
    __hip_bfloat16* qbuf = (__hip_bfloat16*)(wsb + (10l << 20));
    __hip_bfloat16* kbuf = (__hip_bfloat16*)(wsb + (12l << 20));
    __hip_bfloat16* vtb  = (__hip_bfloat16*)(wsb + (14l << 20));
    __hip_bfloat16* aob  = (__hip_bfloat16*)(wsb + (16l << 20));
    __hip_bfloat16* hbb  = (__hip_bfloat16*)(wsb + (18l << 20));
    __hip_bfloat16* catb  = hbb;     // alias (embed phase only)
    __hip_bfloat16* catin = qbuf;    // alias (embed phase only, spans q+k)
    __hip_bfloat16* wb   = (__hip_bfloat16*)(wsb + (26l << 20));
    float*          biascat = (float*)      (wsb + (34l << 20));

    __hip_bfloat16* rpw_t  = wb;
    __hip_bfloat16* ipw_t  = wb + 196608;
    __hip_bfloat16* qkv_t  = wb + 327680;   // per layer: [768][256] (q|k|v)
    __hip_bfloat16* ow_t   = wb + 1114112;
    __hip_bfloat16* ff1w_t = wb + 1376256;
    __hip_bfloat16* ff2w_t = wb + 2424832;
    __hip_bfloat16* head_t = wb + 3473408;

    hipMemsetAsync(head_t, 0, 32768 * 2, stream);

    TDs td;
    td.d[0] = {rpw, rpw_t, 768, 256};
    td.d[1] = {ipw, ipw_t, 512, 256};
    for (int l = 0; l < 4; ++l) {
        td.d[2 + l]  = {qw + l * 65536,  qkv_t + l * 196608 + 0,      256, 256};
        td.d[6 + l]  = {kw + l * 65536,  qkv_t + l * 196608 + 65536,  256, 256};
        td.d[10 + l] = {vw + l * 65536,  qkv_t + l * 196608 + 131072, 256, 256};
        td.d[14 + l] = {ow + l * 65536,  ow_t + l * 65536,  256, 256};
        td.d[18 + l] = {ff1w + l * 262144, ff1w_t + l * 262144, 256, 1024};
        td.d[22 + l] = {ff2w + l * 262144, ff2w_t + l * 262144, 1024, 256};
    }
    td.d[26] = {h1w, head_t + 0 * 22 * 256, 256, 22};
    td.d[27] = {h2w, head_t + 1 * 22 * 256, 256, 22};
    td.d[28] = {h3w, head_t + 2 * 22 * 256, 256, 22};
    transpose_kernel<<<dim3(256, 29), 256, 0, stream>>>(td);

    gather_kernel<<<NTOK, 256, 0, stream>>>(roots, letE, catb, h1b, h2b, h3b, biascat);
    mm_kernel<32, 64, 0><<<dim3(4, 128), 256, 0, stream>>>(
        catb, rpw_t, rpb, tmpf, nullptr, NTOK, 768, 256, nullptr, nullptr, nullptr, nullptr);
    ln_gem_kernel<<<NTOK, 256, 0, stream>>>(tmpf, gem, rlg, rlb, catin);
    mm_kernel<32, 64, 0><<<dim3(4, 128), 256, 0, stream>>>(
        catin, ipw_t, ipb, tmpf, nullptr, NTOK, 512, 256, nullptr, nullptr, nullptr, nullptr);
    ln_pe2_kernel<<<NTOK, 256, 0, stream>>>(tmpf, ilg, ilb, ln1g, ln1b, x, nrm);

    for (int l = 0; l < NLAYER; ++l) {
        mm_kernel<64, 64, 6><<<dim3(12, 64), 256, 0, stream>>>(
            nrm, qkv_t + l * 196608, qb + l * 256, nullptr, qbuf, NTOK, 256, 768,
            kb + l * 256, vb + l * 256, kbuf, vtb);
        attn_mfma_kernel<<<dim3(16, 32), 256, 0, stream>>>(qbuf, kbuf, vtb, aob,
                                                           dsc + l * 8, dss + l * 8);
        mm_wide_ln_kernel<<<dim3(NTOK / 16), 256, 0, stream>>>(
            aob, ow_t + l * 65536, ob + l * 256, x, nrm,
            ln2g + l * 256, ln2b + l * 256, 256);
        mm_kernel<64, 64, 2><<<dim3(16, 64), 256, 0, stream>>>(
            nrm, ff1w_t + l * 262144, ff1b + l * 1024, nullptr, hbb, NTOK, 256, 1024,
            nullptr, nullptr, nullptr, nullptr);
        const float* ng = (l == 3) ? olng : ln1g + (l + 1) * 256;
        const float* nb = (l == 3) ? olnb : ln1b + (l + 1) * 256;
        mm_wide_ln_kernel<<<dim3(NTOK / 16), 256, 0, stream>>>(
            hbb, ff2w_t + l * 262144, ff2b + l * 256, x, nrm, ng, nb, 1024);
    }
    mm_kernel<32, 64, 5><<<dim3(2, 128), 256, 0, stream>>>(
        nrm, head_t, biascat, (float*)d_out, nullptr, NTOK, 256, 128,
        nullptr, nullptr, nullptr, nullptr);
}

// Round 5
// 435.043 us; speedup vs baseline: 3.2793x; 1.0853x over previous
//
#include <hip/hip_runtime.h>
#include <hip/hip_bf16.h>
#include <math.h>

#define NTOK   4096
#define SEQ    1024
#define DMODEL 256
#define NHEAD  8
#define FDIM   1024
#define NLAYER 4

typedef __attribute__((ext_vector_type(8))) short short8v;
typedef __attribute__((ext_vector_type(4))) float f32x4;

#define LDS3(p) ((__attribute__((address_space(3))) unsigned int*)(p))
#define GAS1(p) ((const __attribute__((address_space(1))) unsigned int*)(p))

__device__ __forceinline__ void gl_lds16(const void* g, void* l) {
    __builtin_amdgcn_global_load_lds(GAS1(g), LDS3(l), 16, 0, 0);
}
__device__ __forceinline__ short f2bf(float v) {
    __hip_bfloat16 h = __float2bfloat16(v);
    return __builtin_bit_cast(short, h);
}

// ---------------------------------------------------------------- reductions
__device__ __forceinline__ void blockSum2(float& s1, float& s2, float* red) {
    #pragma unroll
    for (int off = 32; off > 0; off >>= 1) {
        s1 += __shfl_down(s1, off);
        s2 += __shfl_down(s2, off);
    }
    int lane = threadIdx.x & 63, w = threadIdx.x >> 6;
    __syncthreads();
    if (lane == 0) { red[w] = s1; red[4 + w] = s2; }
    __syncthreads();
    s1 = red[0] + red[1] + red[2] + red[3];
    s2 = red[4] + red[5] + red[6] + red[7];
}

// ---------------------------------------------------------------- weight transpose fp32[K][M] -> bf16[M][K]
struct TD { const float* src; __hip_bfloat16* dst; int K; int M; };
struct TDs { TD d[29]; };

__global__ __launch_bounds__(256) void transpose_kernel(TDs p) {
    __shared__ float ld[32][33];
    TD d = p.d[blockIdx.y];
    int tm = (d.M + 31) >> 5;
    int kt = blockIdx.x / tm, mt = blockIdx.x % tm;
    if (kt * 32 >= d.K) return;
    int tx = threadIdx.x & 31, ty = threadIdx.x >> 5;
    #pragma unroll
    for (int r = 0; r < 4; ++r) {
        int k = kt * 32 + ty + r * 8, m = mt * 32 + tx;
        if (m < d.M) ld[ty + r * 8][tx] = d.src[(long)k * d.M + m];
    }
    __syncthreads();
    #pragma unroll
    for (int r = 0; r < 4; ++r) {
        int m = mt * 32 + ty + r * 8, k = kt * 32 + tx;
        if (m < d.M) d.dst[(long)m * d.K + k] = __float2bfloat16(ld[tx][ty + r * 8]);
    }
}

// ---------------------------------------------------------------- MFMA GEMM (2-phase dbuf)
// EPI 0: fp32 store | 2: gelu->bf16 | 5: heads scatter (cols<66) | 6: QKV split
template <int TM, int TN, int EPI>
__global__ __launch_bounds__(256) void mm_kernel(
    const __hip_bfloat16* __restrict__ A, const __hip_bfloat16* __restrict__ Bw,
    const float* __restrict__ bias, float* __restrict__ Cf,
    __hip_bfloat16* __restrict__ Cb, int N, int K, int M,
    const float* __restrict__ b2, const float* __restrict__ b3,
    __hip_bfloat16* __restrict__ Ck, __hip_bfloat16* __restrict__ Cv)
{
    constexpr int BK = 64;
    __shared__ __align__(16) short As[2][TM * BK];
    __shared__ __align__(16) short Bs[2][TN * BK];
    const int tid = threadIdx.x;
    const int lane = tid & 63, wid = tid >> 6;
    const int wr = wid >> 1, wc = wid & 1;
    const int n0 = blockIdx.y * TM, m0 = blockIdx.x * TN;
    const int l15 = lane & 15, g = lane >> 4;
    constexpr int FM = (TM / 32 > 0) ? TM / 32 : 1;
    constexpr int FN = TN / 32;
    f32x4 acc[FM][FN] = {};
    const int nt = K >> 6;

    auto stage = [&](int buf, int k0) {
        constexpr int CA = TM * 8;
        #pragma unroll
        for (int j = 0; j < (CA + 255) / 256; ++j) {
            int cid = tid + j * 256;
            if (CA % 256 == 0 || cid < CA) {
                int r = cid >> 3, sl = cid & 7, ss = sl ^ (r & 7);
                gl_lds16(A + (long)(n0 + r) * K + k0 + ss * 8, (char*)As[buf] + cid * 16);
            }
        }
        constexpr int CB = TN * 8;
        #pragma unroll
        for (int j = 0; j < CB / 256; ++j) {
            int cid = tid + j * 256;
            int r = cid >> 3, sl = cid & 7, ss = sl ^ (r & 7);
            gl_lds16(Bw + (long)(m0 + r) * K + k0 + ss * 8, (char*)Bs[buf] + cid * 16);
        }
    };

    stage(0, 0);
    __syncthreads();
    for (int t = 0; t < nt; ++t) {
        int cur = t & 1;
        if (t + 1 < nt) stage(cur ^ 1, (t + 1) * BK);
        #pragma unroll
        for (int ks = 0; ks < 2; ++ks) {
            short8v af[FM], bfr[FN];
            #pragma unroll
            for (int mi = 0; mi < FM; ++mi) {
                int row = wr * (TM / 2) + mi * 16 + l15;
                int slot = (ks * 4 + g) ^ (row & 7);
                af[mi] = *(const short8v*)((const char*)As[cur] + row * (BK * 2) + slot * 16);
            }
            #pragma unroll
            for (int ni = 0; ni < FN; ++ni) {
                int row = wc * (TN / 2) + ni * 16 + l15;
                int slot = (ks * 4 + g) ^ (row & 7);
                bfr[ni] = *(const short8v*)((const char*)Bs[cur] + row * (BK * 2) + slot * 16);
            }
            #pragma unroll
            for (int mi = 0; mi < FM; ++mi)
                #pragma unroll
                for (int ni = 0; ni < FN; ++ni)
                    acc[mi][ni] = __builtin_amdgcn_mfma_f32_16x16x32_bf16(
                        af[mi], bfr[ni], acc[mi][ni], 0, 0, 0);
        }
        __syncthreads();
    }

    #pragma unroll
    for (int mi = 0; mi < FM; ++mi) {
        #pragma unroll
        for (int ni = 0; ni < FN; ++ni) {
            int colb = m0 + wc * (TN / 2) + ni * 16 + l15;
            float bv;
            if (EPI == 6) bv = (colb < 256) ? bias[colb] : (colb < 512) ? b2[colb - 256] : b3[colb - 512];
            else bv = bias[colb];
            if (EPI == 6 && colb >= 512) {
                int c2 = colb - 512;
                int h = c2 >> 5, dd = c2 & 31;
                int row0 = n0 + wr * (TM / 2) + mi * 16 + g * 4;
                int bb = row0 >> 10, ss = row0 & 1023;
                short4 pk;
                pk.x = f2bf(acc[mi][ni][0] + bv);
                pk.y = f2bf(acc[mi][ni][1] + bv);
                pk.z = f2bf(acc[mi][ni][2] + bv);
                pk.w = f2bf(acc[mi][ni][3] + bv);
                *(short4*)((short*)Cv + ((long)((bb * 8 + h) * 32 + dd) << 10) + ss) = pk;
            } else {
                #pragma unroll
                for (int i = 0; i < 4; ++i) {
                    int row = n0 + wr * (TM / 2) + mi * 16 + g * 4 + i;
                    float v = acc[mi][ni][i] + bv;
                    if (EPI == 0) Cf[(long)row * M + colb] = v;
                    else if (EPI == 2) {
                        v = 0.5f * v * (1.f + erff(v * 0.70710678f));
                        Cb[(long)row * M + colb] = __float2bfloat16(v);
                    } else if (EPI == 5) {
                        if (colb < 66) {
                            int hd = colb / 22, jj = colb - hd * 22;
                            Cf[(long)hd * (NTOK * 22) + (long)row * 22 + jj] = v;
                        }
                    } else if (EPI == 6) {
                        __hip_bfloat16* dst = (colb < 256) ? Cb : Ck;
                        int cc = (colb < 256) ? colb : colb - 256;
                        dst[(long)row * 256 + cc] = __float2bfloat16(v);
                    }
                }
            }
        }
    }
}

// ---------------------------------------------------------------- wide GEMM + residual + LN (2-phase dbuf)
// TM=16 rows/block (grid 256), full 256-wide, 4 waves side by side.
__global__ __launch_bounds__(256) void mm_wide_ln_kernel(
    const __hip_bfloat16* __restrict__ A, const __hip_bfloat16* __restrict__ Bw,
    const float* __restrict__ bias, float* __restrict__ xio,
    __hip_bfloat16* __restrict__ nrm, const float* __restrict__ lng,
    const float* __restrict__ lnb, int K)
{
    constexpr int BK = 64;
    __shared__ __align__(16) short As[2][16 * BK];
    __shared__ __align__(16) short Bs[2][256 * BK];
    __shared__ float2 red2[4][16];
    const int tid = threadIdx.x;
    const int lane = tid & 63, wid = tid >> 6;
    const int l15 = lane & 15, g = lane >> 4;
    const int n0 = blockIdx.x * 16;
    f32x4 acc[4] = {};
    const int nt = K >> 6;

    auto stage = [&](int buf, int k0) {
        if (tid < 128) {
            int r = tid >> 3, sl = tid & 7, ss = sl ^ (r & 7);
            gl_lds16(A + (long)(n0 + r) * K + k0 + ss * 8, (char*)As[buf] + tid * 16);
        }
        #pragma unroll
        for (int j = 0; j < 8; ++j) {
            int cid = tid + j * 256;
            int r = cid >> 3, sl = cid & 7, ss = sl ^ (r & 7);
            gl_lds16(Bw + (long)r * K + k0 + ss * 8, (char*)Bs[buf] + cid * 16);
        }
    };

    stage(0, 0);
    __syncthreads();
    for (int t = 0; t < nt; ++t) {
        int cur = t & 1;
        if (t + 1 < nt) stage(cur ^ 1, (t + 1) * BK);
        #pragma unroll
        for (int ks = 0; ks < 2; ++ks) {
            short8v af;
            {
                int slot = (ks * 4 + g) ^ (l15 & 7);
                af = *(const short8v*)((const char*)As[cur] + l15 * (BK * 2) + slot * 16);
            }
            #pragma unroll
            for (int ni = 0; ni < 4; ++ni) {
                int brow = wid * 64 + ni * 16 + l15;
                int slot = (ks * 4 + g) ^ (brow & 7);
                short8v bfr = *(const short8v*)((const char*)Bs[cur] + brow * (BK * 2) + slot * 16);
                acc[ni] = __builtin_amdgcn_mfma_f32_16x16x32_bf16(af, bfr, acc[ni], 0, 0, 0);
            }
        }
        __syncthreads();
    }

    float pvt[4][4];
    float rs[4] = {0.f, 0.f, 0.f, 0.f}, rq[4] = {0.f, 0.f, 0.f, 0.f};
    #pragma unroll
    for (int ni = 0; ni < 4; ++ni) {
        int col = wid * 64 + ni * 16 + l15;
        float bv = bias[col];
        #pragma unroll
        for (int i = 0; i < 4; ++i) {
            int row = n0 + g * 4 + i;
            float v = acc[ni][i] + bv + xio[(long)row * 256 + col];
            pvt[ni][i] = v;
            rs[i] += v;
            rq[i] += v * v;
        }
    }
    #pragma unroll
    for (int i = 0; i < 4; ++i) {
        #pragma unroll
        for (int off = 8; off; off >>= 1) {
            rs[i] += __shfl_xor(rs[i], off);
            rq[i] += __shfl_xor(rq[i], off);
        }
    }
    __syncthreads();
    if (l15 == 0) {
        #pragma unroll
        for (int i = 0; i < 4; ++i)
            red2[wid][g * 4 + i] = make_float2(rs[i], rq[i]);
    }
    __syncthreads();
    #pragma unroll
    for (int i = 0; i < 4; ++i) {
        int lr = g * 4 + i;
        float s1 = red2[0][lr].x + red2[1][lr].x + red2[2][lr].x + red2[3][lr].x;
        float s2 = red2[0][lr].y + red2[1][lr].y + red2[2][lr].y + red2[3][lr].y;
        float mean = s1 * (1.f / 256.f);
        float var = s2 * (1.f / 256.f) - mean * mean;
        float rsx = rsqrtf(var + 1e-5f);
        int row = n0 + lr;
        #pragma unroll
        for (int ni = 0; ni < 4; ++ni) {
            int col = wid * 64 + ni * 16 + l15;
            float v = pvt[ni][i];
            xio[(long)row * 256 + col] = v;
            nrm[(long)row * 256 + col] =
                __float2bfloat16((v - mean) * rsx * lng[col] + lnb[col]);
        }
    }
}

// ---------------------------------------------------------------- MFMA flash attention (swapped QK^T, lane-owns-column softmax)
__global__ __launch_bounds__(256) void attn_mfma_kernel(
    const __hip_bfloat16* __restrict__ Q, const __hip_bfloat16* __restrict__ Kx,
    const __hip_bfloat16* __restrict__ Vt, __hip_bfloat16* __restrict__ Oa,
    const float* __restrict__ dsc, const float* __restrict__ dss)
{
    __shared__ __align__(16) short Qs[64 * 32];
    __shared__ __align__(16) short Ks[2][64 * 32];
    __shared__ __align__(16) short Vs[2][32 * 64];
    __shared__ __align__(16) short Ps[4 * 16 * 64];
    const int tid = threadIdx.x, lane = tid & 63, wid = tid >> 6;
    const int qt = blockIdx.x, bh = blockIdx.y, b = bh >> 3, h = bh & 7;
    const float pen = fabsf(dsc[h] * (1.f - 0.5f * dss[h]));
    const int l15 = lane & 15, g = lane >> 4;
    const float scale = 0.17677669529663689f;

    auto stageKV = [&](int buf, int kt) {
        int r = tid >> 2, sl = tid & 3, ss = sl ^ (r & 3);
        gl_lds16(Kx + ((long)(b * SEQ + kt * 64 + r) * DMODEL + h * 32) + ss * 8,
                 (char*)Ks[buf] + tid * 16);
        int d = tid >> 3, sl8 = tid & 7, ss8 = sl8 ^ (d & 7);
        gl_lds16(Vt + ((long)(bh * 32 + d) << 10) + kt * 64 + ss8 * 8,
                 (char*)Vs[buf] + tid * 16);
    };

    {   // stage Q tile (64 rows x 32 d)
        int r = tid >> 2, sl = tid & 3, ss = sl ^ (r & 3);
        gl_lds16(Q + ((long)(b * SEQ + qt * 64 + r) * DMODEL + h * 32) + ss * 8,
                 (char*)Qs + tid * 16);
    }
    stageKV(0, 0);
    __syncthreads();

    // Q fragment is constant across kt: hoist
    short8v bq;
    {
        int row = wid * 16 + l15;
        int slot = g ^ (row & 3);
        bq = *(const short8v*)((const char*)Qs + row * 64 + slot * 16);
    }

    float m = -1e30f, l = 0.f;            // per-thread: q-column = l15
    f32x4 oacc[2] = {};
    const float qpos = (float)(qt * 64 + wid * 16 + l15);
    char* pbase = (char*)Ps + wid * 2048 + l15 * 128;

    for (int kt = 0; kt < 16; ++kt) {
        int cur = kt & 1;
        if (kt < 15) stageKV(cur ^ 1, kt + 1);

        // swapped QK^T: D[key][q]  (thread: q=l15, keys = ni*16 + g*4 + i)
        float s[4][4];
        float smax = -1e30f;
        #pragma unroll
        for (int ni = 0; ni < 4; ++ni) {
            int krow = ni * 16 + l15;
            int slot = g ^ (krow & 3);
            short8v ak = *(const short8v*)((const char*)Ks[cur] + krow * 64 + slot * 16);
            f32x4 z = {0.f, 0.f, 0.f, 0.f};
            f32x4 sa = __builtin_amdgcn_mfma_f32_16x16x32_bf16(ak, bq, z, 0, 0, 0);
            float kbase = (float)(kt * 64 + ni * 16 + g * 4);
            #pragma unroll
            for (int i = 0; i < 4; ++i) {
                float v = sa[i] * scale - pen * fabsf(qpos - (kbase + (float)i));
                s[ni][i] = v;
                smax = fmaxf(smax, v);
            }
        }
        smax = fmaxf(smax, __shfl_xor(smax, 16));
        smax = fmaxf(smax, __shfl_xor(smax, 32));
        float mn = fmaxf(m, smax);
        float fac = __expf(m - mn);
        m = mn;
        float ps = 0.f;
        #pragma unroll
        for (int ni = 0; ni < 4; ++ni) {
            short4 pk;
            #pragma unroll
            for (int i = 0; i < 4; ++i) {
                float p = __expf(s[ni][i] - mn);
                ps += p;
                ((short*)&pk)[i] = f2bf(p);
            }
            int slot = (ni * 2 + (g >> 1)) ^ (l15 & 7);
            *(short4*)(pbase + slot * 16 + (g & 1) * 8) = pk;
        }
        ps += __shfl_xor(ps, 16);
        ps += __shfl_xor(ps, 32);
        l = l * fac + ps;

        // broadcast fac to this thread's oacc rows (q = g*4+i)
        float facr[4];
        #pragma unroll
        for (int i = 0; i < 4; ++i) facr[i] = __shfl(fac, g * 4 + i);
        #pragma unroll
        for (int n2 = 0; n2 < 2; ++n2)
            #pragma unroll
            for (int i = 0; i < 4; ++i) oacc[n2][i] *= facr[i];

        // PV
        #pragma unroll
        for (int ks = 0; ks < 2; ++ks) {
            int slot = (ks * 4 + g) ^ (l15 & 7);
            short8v pa = *(const short8v*)(pbase + slot * 16);
            #pragma unroll
            for (int n2 = 0; n2 < 2; ++n2) {
                int d = n2 * 16 + l15;
                int vslot = (ks * 4 + g) ^ (d & 7);
                short8v vb = *(const short8v*)((const char*)Vs[cur] + d * 128 + vslot * 16);
                oacc[n2] = __builtin_amdgcn_mfma_f32_16x16x32_bf16(pa, vb, oacc[n2], 0, 0, 0);
            }
        }
        __syncthreads();
    }
    float lr[4];
    #pragma unroll
    for (int i = 0; i < 4; ++i) lr[i] = __shfl(l, g * 4 + i);
    #pragma unroll
    for (int n2 = 0; n2 < 2; ++n2) {
        #pragma unroll
        for (int i = 0; i < 4; ++i) {
            float v = oacc[n2][i] / lr[i];
            long row = b * SEQ + qt * 64 + wid * 16 + g * 4 + i;
            Oa[row * DMODEL + h * 32 + n2 * 16 + l15] = __float2bfloat16(v);
        }
    }
}

// ---------------------------------------------------------------- small fused kernels
__global__ __launch_bounds__(256) void gather_kernel(
    const int* __restrict__ roots, const float* __restrict__ letE,
    __hip_bfloat16* __restrict__ cat,
    const float* __restrict__ h1b, const float* __restrict__ h2b,
    const float* __restrict__ h3b, float* __restrict__ biascat)
{
    const int n = blockIdx.x, t = threadIdx.x;
    int r0 = roots[n * 3 + 0], r1 = roots[n * 3 + 1], r2 = roots[n * 3 + 2];
    cat[(long)n * 768 + t]       = __float2bfloat16(letE[r0 * DMODEL + t]);
    cat[(long)n * 768 + 256 + t] = __float2bfloat16(letE[r1 * DMODEL + t]);
    cat[(long)n * 768 + 512 + t] = __float2bfloat16(letE[r2 * DMODEL + t]);
    if (n == 0 && t < 66)
        biascat[t] = (t < 22) ? h1b[t] : (t < 44) ? h2b[t - 22] : h3b[t - 44];
}

__global__ __launch_bounds__(256) void ln_gem_kernel(
    const float* __restrict__ tmpf, const float* __restrict__ gem,
    const float* __restrict__ gg, const float* __restrict__ gb,
    __hip_bfloat16* __restrict__ catin)
{
    __shared__ float red[8];
    const int n = blockIdx.x, t = threadIdx.x;
    const float LC = 0.0359778921f;
    float v = tmpf[(long)n * DMODEL + t];
    float s1 = v, s2 = v * v;
    blockSum2(s1, s2, red);
    float mean = s1 * (1.f / 256.f);
    float var = s2 * (1.f / 256.f) - mean * mean;
    catin[(long)n * 512 + t] =
        __float2bfloat16((v - mean) * rsqrtf(var + 1e-5f) * gg[t] + gb[t]);
    float gv = gem[n];
    int j = (t < 128) ? t : t - 128;
    float ang = gv * 500.f * expf(-(float)(2 * j) * LC);
    catin[(long)n * 512 + 256 + t] = __float2bfloat16((t < 128) ? sinf(ang) : cosf(ang));
}

// x = LN(tmpf + PE; ilg,ilb); nrm = LN(x; g1,b1)  (layer0 pre-attn norm)
__global__ __launch_bounds__(256) void ln_pe2_kernel(
    const float* __restrict__ tmpf, const float* __restrict__ gg,
    const float* __restrict__ gb, const float* __restrict__ g1,
    const float* __restrict__ b1, float* __restrict__ x,
    __hip_bfloat16* __restrict__ nrm)
{
    __shared__ float red[8];
    const int n = blockIdx.x, t = threadIdx.x;
    const int s = n & (SEQ - 1);
    const float LC = 0.0359778921f;
    float pos = (float)(SEQ - 1 - s);
    float dv = expf(-(float)(t & ~1) * LC);
    float pe = (t & 1) ? cosf(pos * dv) : sinf(pos * dv);
    float v = tmpf[(long)n * DMODEL + t] + pe;
    float s1 = v, s2 = v * v;
    blockSum2(s1, s2, red);
    float mean = s1 * (1.f / 256.f);
    float var = s2 * (1.f / 256.f) - mean * mean;
    float xv = (v - mean) * rsqrtf(var + 1e-5f) * gg[t] + gb[t];
    x[(long)n * DMODEL + t] = xv;
    s1 = xv; s2 = xv * xv;
    blockSum2(s1, s2, red);
    mean = s1 * (1.f / 256.f);
    var = s2 * (1.f / 256.f) - mean * mean;
    nrm[(long)n * DMODEL + t] =
        __float2bfloat16((xv - mean) * rsqrtf(var + 1e-5f) * g1[t] + b1[t]);
}

// ---------------------------------------------------------------- launch
extern "C" void kernel_launch(void* const* d_in, const int* in_sizes, int n_in,
                              void* d_out, int out_size, void* d_ws, size_t ws_size,
                              hipStream_t stream)
{
    const int*   roots = (const int*)  d_in[0];
    const float* gem   = (const float*)d_in[1];
    const float* letE  = (const float*)d_in[2];
    const float* rpw   = (const float*)d_in[3];
    const float* rpb   = (const float*)d_in[4];
    const float* rlg   = (const float*)d_in[5];
    const float* rlb   = (const float*)d_in[6];
    const float* ipw   = (const float*)d_in[7];
    const float* ipb   = (const float*)d_in[8];
    const float* ilg   = (const float*)d_in[9];
    const float* ilb   = (const float*)d_in[10];
    const float* qw    = (const float*)d_in[11];
    const float* qb    = (const float*)d_in[12];
    const float* kw    = (const float*)d_in[13];
    const float* kb    = (const float*)d_in[14];
    const float* vw    = (const float*)d_in[15];
    const float* vb    = (const float*)d_in[16];
    const float* ow    = (const float*)d_in[17];
    const float* ob    = (const float*)d_in[18];
    const float* dsc   = (const float*)d_in[19];
    const float* dss   = (const float*)d_in[20];
    const float* ff1w  = (const float*)d_in[21];
    const float* ff1b  = (const float*)d_in[22];
    const float* ff2w  = (const float*)d_in[23];
    const float* ff2b  = (const float*)d_in[24];
    const float* ln1g  = (const float*)d_in[25];
    const float* ln1b  = (const float*)d_in[26];
    const float* ln2g  = (const float*)d_in[27];
    const float* ln2b  = (const float*)d_in[28];
    const float* olng  = (const float*)d_in[29];
    const float* olnb  = (const float*)d_in[30];
    const float* h1w   = (const float*)d_in[31];
    const float* h1b   = (const float*)d_in[32];
    const float* h2w   = (const float*)d_in[33];
    const float* h2b   = (const float*)d_in[34];
    const float* h3w   = (const float*)d_in[35];
    const float* h3b   = (const float*)d_in[36];

    char* wsb = (char*)d_ws;
    float*          x    = (float*)         (wsb + (0l  << 20));
    float*          tmpf = (float*)         (wsb + (4l  << 20));
    __hip_bfloat16* nrm  = (__hip_bfloat16*)(wsb + (8l  << 20));
    __hip_bfloat16* qbuf = (__hip_bfloat16*)(wsb + (10l << 20));
    __hip_bfloat16* kbuf = (__hip_bfloat16*)(wsb + (12l << 20));
    __hip_bfloat16* vtb  = (__hip_bfloat16*)(wsb + (14l << 20));
    __hip_bfloat16* aob  = (__hip_bfloat16*)(wsb + (16l << 20));
    __hip_bfloat16* hbb  = (__hip_bfloat16*)(wsb + (18l << 20));
    __hip_bfloat16* catb  = hbb;     // alias (embed phase only)
    __hip_bfloat16* catin = qbuf;    // alias (embed phase only, spans q+k)
    __hip_bfloat16* wb   = (__hip_bfloat16*)(wsb + (26l << 20));
    float*          biascat = (float*)      (wsb + (34l << 20));

    __hip_bfloat16* rpw_t  = wb;
    __hip_bfloat16* ipw_t  = wb + 196608;
    __hip_bfloat16* qkv_t  = wb + 327680;   // per layer: [768][256] (q|k|v)
    __hip_bfloat16* ow_t   = wb + 1114112;
    __hip_bfloat16* ff1w_t = wb + 1376256;
    __hip_bfloat16* ff2w_t = wb + 2424832;
    __hip_bfloat16* head_t = wb + 3473408;

    hipMemsetAsync(head_t, 0, 32768 * 2, stream);

    TDs td;
    td.d[0] = {rpw, rpw_t, 768, 256};
    td.d[1] = {ipw, ipw_t, 512, 256};
    for (int l = 0; l < 4; ++l) {
        td.d[2 + l]  = {qw + l * 65536,  qkv_t + l * 196608 + 0,      256, 256};
        td.d[6 + l]  = {kw + l * 65536,  qkv_t + l * 196608 + 65536,  256, 256};
        td.d[10 + l] = {vw + l * 65536,  qkv_t + l * 196608 + 131072, 256, 256};
        td.d[14 + l] = {ow + l * 65536,  ow_t + l * 65536,  256, 256};
        td.d[18 + l] = {ff1w + l * 262144, ff1w_t + l * 262144, 256, 1024};
        td.d[22 + l] = {ff2w + l * 262144, ff2w_t + l * 262144, 1024, 256};
    }
    td.d[26] = {h1w, head_t + 0 * 22 * 256, 256, 22};
    td.d[27] = {h2w, head_t + 1 * 22 * 256, 256, 22};
    td.d[28] = {h3w, head_t + 2 * 22 * 256, 256, 22};
    transpose_kernel<<<dim3(256, 29), 256, 0, stream>>>(td);

    gather_kernel<<<NTOK, 256, 0, stream>>>(roots, letE, catb, h1b, h2b, h3b, biascat);
    mm_kernel<32, 64, 0><<<dim3(4, 128), 256, 0, stream>>>(
        catb, rpw_t, rpb, tmpf, nullptr, NTOK, 768, 256, nullptr, nullptr, nullptr, nullptr);
    ln_gem_kernel<<<NTOK, 256, 0, stream>>>(tmpf, gem, rlg, rlb, catin);
    mm_kernel<32, 64, 0><<<dim3(4, 128), 256, 0, stream>>>(
        catin, ipw_t, ipb, tmpf, nullptr, NTOK, 512, 256, nullptr, nullptr, nullptr, nullptr);
    ln_pe2_kernel<<<NTOK, 256, 0, stream>>>(tmpf, ilg, ilb, ln1g, ln1b, x, nrm);

    for (int l = 0; l < NLAYER; ++l) {
        mm_kernel<64, 64, 6><<<dim3(12, 64), 256, 0, stream>>>(
            nrm, qkv_t + l * 196608, qb + l * 256, nullptr, qbuf, NTOK, 256, 768,
            kb + l * 256, vb + l * 256, kbuf, vtb);
        attn_mfma_kernel<<<dim3(16, 32), 256, 0, stream>>>(qbuf, kbuf, vtb, aob,
                                                           dsc + l * 8, dss + l * 8);
        mm_wide_ln_kernel<<<dim3(NTOK / 16), 256, 0, stream>>>(
            aob, ow_t + l * 65536, ob + l * 256, x, nrm,
            ln2g + l * 256, ln2b + l * 256, 256);
        mm_kernel<64, 64, 2><<<dim3(16, 64), 256, 0, stream>>>(
            nrm, ff1w_t + l * 262144, ff1b + l * 1024, nullptr, hbb, NTOK, 256, 1024,
            nullptr, nullptr, nullptr, nullptr);
        const float* ng = (l == 3) ? olng : ln1g + (l + 1) * 256;
        const float* nb = (l == 3) ? olnb : ln1b + (l + 1) * 256;
        mm_wide_ln_kernel<<<dim3(NTOK / 16), 256, 0, stream>>>(
            hbb, ff2w_t + l * 262144, ff2b + l * 256, x, nrm, ng, nb, 1024);
    }
    mm_kernel<32, 64, 5><<<dim3(2, 128), 256, 0, stream>>>(
        nrm, head_t, biascat, (float*)d_out, nullptr, NTOK, 256, 128,
        nullptr, nullptr, nullptr, nullptr);
}